// Round 5
// baseline (22593.993 us; speedup 1.0000x reference)
//
#include <hip/hip_runtime.h>
#include <cstdint>
#include <cstddef>

namespace {

constexpr int D   = 1024;
constexpr int NB  = 20;
constexpr int B   = 8;
constexpr int S   = 2048;
constexpr int NWG = 32;      // workgroups cooperating per batch
constexpr float EPS = 1e-8f;

typedef __attribute__((ext_vector_type(4))) float f4_t;
typedef __attribute__((ext_vector_type(8))) short s8_t;
typedef unsigned long long u64_t;

__device__ __forceinline__ unsigned short f2bf(float f) {
  unsigned u = __float_as_uint(f);
  u += 0x7fffu + ((u >> 16) & 1u);     // RNE
  return (unsigned short)(u >> 16);
}
__device__ __forceinline__ float bf2f(unsigned short h) {
  return __uint_as_float(((unsigned)h) << 16);
}
__device__ __forceinline__ float u64lo(u64_t x) { return __uint_as_float((unsigned)x); }
__device__ __forceinline__ float u64hi(u64_t x) { return __uint_as_float((unsigned)(x >> 32)); }
__device__ __forceinline__ float rcp_f(float x) { return __builtin_amdgcn_rcpf(x); }
__device__ __forceinline__ float sigm_fast(float x) { return rcp_f(1.0f + __expf(-x)); }
__device__ __forceinline__ float tanh_fast(float x) {
  const float e = __expf(2.0f * x);
  return 1.0f - 2.0f * rcp_f(e + 1.0f);
}

#define MFMA(a, b, c) __builtin_amdgcn_mfma_f32_16x16x32_bf16((a), (b), (c), 0, 0, 0)
#define ALOAD64(p) __hip_atomic_load((p), __ATOMIC_RELAXED, __HIP_MEMORY_SCOPE_AGENT)
#define ASTORE64(p, v) __hip_atomic_store((p), (v), __ATOMIC_RELAXED, __HIP_MEMORY_SCOPE_AGENT)
#define ALOAD32(p) __hip_atomic_load((p), __ATOMIC_RELAXED, __HIP_MEMORY_SCOPE_AGENT)
#define ASTORE32(p, v) __hip_atomic_store((p), (v), __ATOMIC_RELAXED, __HIP_MEMORY_SCOPE_AGENT)

// ---- workspace layout (bytes) ----
constexpr size_t OFF_HBUF = 0;                                   // u32 [2][B][NB][512]  (bf16 pairs)
constexpr size_t OFF_NORM = OFF_HBUF + 2ull * B * NB * 512 * 4;  // f32 [2][B][NB][NWG]
constexpr size_t OFF_CTR  = OFF_NORM + 2ull * B * NB * NWG * 4;  // u32 [B][32][4]: per-block per-wave flag slots
constexpr size_t OFF_KV   = OFF_CTR + (size_t)B * 32 * 4 * 4;    // f32 [NB][D]
constexpr size_t OFF_KX   = OFF_KV + (size_t)NB * D * 4;         // f32 [B*S][NB]
constexpr size_t OFF_UHI  = OFF_KX + (size_t)B * S * NB * 4;     // u16 [D][D]
constexpr size_t OFF_ULO  = OFF_UHI + (size_t)D * D * 2;
constexpr size_t OFF_WHI  = OFF_ULO + (size_t)D * D * 2;
constexpr size_t OFF_WLO  = OFF_WHI + (size_t)D * D * 2;

// ---------------- init kernels ----------------

__global__ void k_convert(const float* __restrict__ U, const float* __restrict__ W,
                          unsigned short* __restrict__ Uhi, unsigned short* __restrict__ Ulo,
                          unsigned short* __restrict__ Whi, unsigned short* __restrict__ Wlo) {
  const int n = D * D;
  for (int i = blockIdx.x * blockDim.x + threadIdx.x; i < n; i += gridDim.x * blockDim.x) {
    float u = U[i];
    unsigned short h = f2bf(u);
    Uhi[i] = h;
    Ulo[i] = f2bf(u - bf2f(h));
    float w = W[i];
    h = f2bf(w);
    Whi[i] = h;
    Wlo[i] = f2bf(w - bf2f(h));
  }
}

// KV[i][j] = keys[i] . V[j]
__global__ void k_kv(const float* __restrict__ keys, const float* __restrict__ V,
                     float* __restrict__ KV) {
  const int tid = threadIdx.x;
  const int j = blockIdx.x * 64 + (tid >> 2);
  const int kq = tid & 3;
  const f4_t* v4 = (const f4_t*)(V + (size_t)j * D + kq * 256);
  const f4_t* k4base = (const f4_t*)keys;
  float acc[NB];
#pragma unroll
  for (int i = 0; i < NB; ++i) acc[i] = 0.f;
  for (int q = 0; q < 64; ++q) {
    const f4_t v = v4[q];
#pragma unroll
    for (int i = 0; i < NB; ++i) {
      const f4_t kk = k4base[i * 256 + kq * 64 + q];
      acc[i] += kk[0] * v[0] + kk[1] * v[1] + kk[2] * v[2] + kk[3] * v[3];
    }
  }
#pragma unroll
  for (int i = 0; i < NB; ++i) {
    float s = acc[i];
    s += __shfl_xor(s, 1);
    s += __shfl_xor(s, 2);
    if (kq == 0) KV[(size_t)i * D + j] = s;
  }
}

// KX[bt][i] = keys[i] . (e[bt]+m[bt])
__global__ void k_kx(const float* __restrict__ e, const float* __restrict__ m,
                     const float* __restrict__ keys, float* __restrict__ KX) {
  __shared__ f4_t xs[256];
  __shared__ float part[NB][8];
  const int bt = blockIdx.x, tid = threadIdx.x;
  xs[tid] = ((const f4_t*)e)[(size_t)bt * 256 + tid] + ((const f4_t*)m)[(size_t)bt * 256 + tid];
  __syncthreads();
  if (tid < 160) {
    const int i = tid >> 3, s8 = tid & 7;
    float acc = 0.f;
    const f4_t* k4 = (const f4_t*)keys + i * 256 + s8 * 32;
    for (int q = 0; q < 32; ++q) {
      const f4_t kk = k4[q];
      const f4_t xx = xs[s8 * 32 + q];
      acc += kk[0] * xx[0] + kk[1] * xx[1] + kk[2] * xx[2] + kk[3] * xx[3];
    }
    part[i][s8] = acc;
  }
  __syncthreads();
  if (tid < NB) {
    float s = 0.f;
#pragma unroll
    for (int q = 0; q < 8; ++q) s += part[tid][q];
    KX[(size_t)bt * NB + tid] = s;
  }
}

__global__ void k_state(const float* __restrict__ state, unsigned* __restrict__ Hbuf,
                        float* __restrict__ NormP, int* __restrict__ ctr) {
  const int idx = blockIdx.x * 256 + threadIdx.x;
  if (idx < B * NB * 512) {
    const int r = idx % (NB * 512);
    const int i = r >> 9, d2 = (r & 511) << 1;
    const unsigned short a = f2bf(state[i * D + d2]);
    const unsigned short c = f2bf(state[i * D + d2 + 1]);
    Hbuf[idx] = (unsigned)a | ((unsigned)c << 16);
  }
  const int j = idx - B * NB * 512;
  if (j >= 0 && j < B * NB * NWG) NormP[j] = 1.0f / 32.0f;  // sumsq=1 -> s=1 exactly
  const int q = idx - B * NB * 512 - B * NB * NWG;
  if (q >= 0 && q < B * 32 * 4) ctr[q] = 0;
}

// ---------------- persistent recurrence kernel ----------------
// 256 blocks x 256 threads (4 waves). Block = batch x column-slice-of-32.
//   * batch = blockIdx & 7 -> all 32 blocks of a batch on ONE XCD (round-4
//     counters proved it: FETCH 3.34GB -> 0.47GB; redundant e/m reads served
//     from that XCD's L2). 4 waves (round-4 8-wave split regressed: phase is
//     issue-bound; 2 waves/SIMD just time-multiplex the pipes).
//   * ONE barrier per phase. Wave-locality: each wave's MFMA reads exactly the
//     hnA/xtA chunk it gathers+stages itself (stage blkk=tid>>1 spans the
//     wave's own MFMA k-block range), so staging needs only a per-wave
//     lgkmcnt(0), no block barrier. The publish release is per-wave too:
//     vmcnt is per-wave state, so each publishing wave (0..2; tid<160 spans
//     them) drains its own stores and sets its own flag slot ctr[b][wg][wv].
//     Pollers require all 3 slots of all 32 blocks >= t+1 (96 words, 3
//     coalesced loads/lane), which also carries NormP/Hbuf visibility.
// Parity safety (2-deep Hbuf/NormP): flag[wg][*] >= t+1 implies block wg
// passed S1(t), which is after ALL its waves' h^t gather loads completed
// (gather -> stage -> MFMA(t) -> S1 -> update -> drain -> flag, per-wave
// program order + barrier). A writer of h^{t+2} (same parity as h^t) polled
// >= t+1 before its update, so it cannot overwrite a slot still being read.

struct __align__(16) LdsT {
  unsigned short hnA[NB * 1024];    // raw bf16 h, swizzled               (40 KB)
  unsigned short xtA[2][1024];      // xt hi/lo rows                       (4 KB)
  float credU[4][2][2][16][20];     // [wv][mt][nt][row][col pad20]       (20 KB)
  float wxAcc[4][2][16];            // [wv][nt][col]
  float gAcc[4][2][16];             // [wv][mt][col]
  float KVs[NB][32];
  float ownH[NB][32];               // fp32 unnormalized h slice
  float pad_force_1_block_per_cu[3072];  // lift LDS >80KB so 2 blocks never share a CU
};

__device__ __forceinline__ void build_xt(unsigned short* xt /* [2][1024] */, int tid, f4_t x) {
  const unsigned short h0 = f2bf(x[0]), h1 = f2bf(x[1]), h2 = f2bf(x[2]), h3 = f2bf(x[3]);
  const unsigned short u0 = f2bf(x[0] - bf2f(h0)), u1 = f2bf(x[1] - bf2f(h1));
  const unsigned short u2 = f2bf(x[2] - bf2f(h2)), u3 = f2bf(x[3] - bf2f(h3));
  const int kp = tid << 2;
  *(unsigned*)&xt[kp] = (unsigned)h0 | ((unsigned)h1 << 16);
  *(unsigned*)&xt[kp + 2] = (unsigned)h2 | ((unsigned)h3 << 16);
  *(unsigned*)&xt[1024 + kp] = (unsigned)u0 | ((unsigned)u1 << 16);
  *(unsigned*)&xt[1024 + kp + 2] = (unsigned)u2 | ((unsigned)u3 << 16);
}

__device__ __forceinline__ void stage_h(unsigned short* hn, int tid, const u64_t* hv) {
  const int blkk = tid >> 1;
  const int half = (tid & 1) << 2;
#pragma unroll
  for (int j = 0; j < 20; ++j)
    *(u64_t*)&hn[(j << 10) + ((blkk ^ (j & 15)) << 3) + half] = hv[j];
}

// lds-only barrier: LDS writes visible, VMEM ops stay in flight across it.
__device__ __forceinline__ void bar_lds() {
  asm volatile("s_waitcnt lgkmcnt(0)\n\ts_barrier" ::: "memory");
}

// poll all 32 blocks x 3 wave-slots >= tgt; lanes 0..31 (dup'd in 32..63)
// each read the 3 slots of one block. Compiler barrier at exit keeps the
// subsequent gather loads from being hoisted above the poll.
__device__ __forceinline__ void poll96(const unsigned* fb, int ln31, unsigned tgt) {
  const unsigned* p = fb + (ln31 << 2);
  for (;;) {
    const unsigned v0 = ALOAD32(p);
    const unsigned v1 = ALOAD32(p + 1);
    const unsigned v2 = ALOAD32(p + 2);
    unsigned mn = v0 < v1 ? v0 : v1;
    mn = mn < v2 ? mn : v2;
    if (__ballot(mn >= tgt) == ~0ull) break;
    __builtin_amdgcn_s_sleep(1);
  }
  asm volatile("" ::: "memory");
}

__launch_bounds__(256, 1)
__global__ void k_rnn(const float* __restrict__ e, const float* __restrict__ m,
                      const float* __restrict__ state,
                      const float* __restrict__ KX, const float* __restrict__ KV,
                      const unsigned short* __restrict__ Uhi, const unsigned short* __restrict__ Ulo,
                      const unsigned short* __restrict__ Whi, const unsigned short* __restrict__ Wlo,
                      unsigned* __restrict__ Hbuf, float* __restrict__ NormP,
                      int* __restrict__ ctr, float* __restrict__ out) {
  __shared__ LdsT L;
  const int tid = threadIdx.x;
  const int b = blockIdx.x & 7;                   // batch 0..7 == XCD (heuristic)
  const int wg = blockIdx.x >> 3;                 // column slice 0..31
  const int wv = tid >> 6;
  const int ln = tid & 63;
  const int l15 = ln & 15;
  const int lo4 = ln >> 4;
  const int ln31 = tid & 31;
  unsigned* ctrp = (unsigned*)ctr + b * 128;      // [32][4] flag slots of this batch

  // resident B-fragments: U and W column slices, bf16 hi/lo, this wave's k-chunk.
  s8_t BUh[2][8], BUl[2][8], BWh[2][8], BWl[2][8];
  {
    const int rowb = (wg << 5) + l15;
#pragma unroll
    for (int nt = 0; nt < 2; ++nt)
#pragma unroll
      for (int kf = 0; kf < 8; ++kf) {
        const size_t off = (size_t)(rowb + nt * 16) * D + (wv << 8) + (kf << 5) + (lo4 << 3);
        BUh[nt][kf] = *(const s8_t*)(Uhi + off);
        BUl[nt][kf] = *(const s8_t*)(Ulo + off);
        BWh[nt][kf] = *(const s8_t*)(Whi + off);
        BWl[nt][kf] = *(const s8_t*)(Wlo + off);
      }
  }
  if (tid < 160) {
    const int i = tid >> 3, c4 = (tid & 7) << 2;
    *(f4_t*)&L.ownH[i][c4] = *(const f4_t*)(state + (size_t)i * D + (wg << 5) + c4);
    *(f4_t*)&L.KVs[i][c4] = *(const f4_t*)(KV + (size_t)i * D + (wg << 5) + c4);
  }

  f4_t evv, mvv;
  float sreg = 1.f;   // exact: initial state pre-normalized (NormP=1/32)
  float kxreg = 0.f;

  // ---- bootstrap: stage step 0 ----
  {
    u64_t hv[20];
    const u64_t* hb8 = (const u64_t*)Hbuf + (size_t)(0 * B + b) * (NB * 256);
#pragma unroll
    for (int j = 0; j < 20; ++j) hv[j] = ALOAD64(hb8 + j * 256 + tid);
    const f4_t x0 = ((const f4_t*)e)[(size_t)(b * S) * 256 + tid] +
                    ((const f4_t*)m)[(size_t)(b * S) * 256 + tid];
    build_xt(&L.xtA[0][0], tid, x0);
    stage_h(L.hnA, tid, hv);
    if (tid < 160) kxreg = KX[(size_t)(b * S) * NB + (tid >> 3)];
    evv = ((const f4_t*)e)[(size_t)(b * S + 1) * 256 + tid];
    mvv = ((const f4_t*)m)[(size_t)(b * S + 1) * 256 + tid];
  }
  __syncthreads();

  for (int t = 0; t < S; ++t) {
    const int nxt2 = (t + 1) & 1;

    // ---- MFMA: h@U^T (hi/lo), x@W^T (hi/lo), x.h gate (all wave-local LDS) ----
    f4_t cU00 = {0, 0, 0, 0}, cU01 = {0, 0, 0, 0}, cU10 = {0, 0, 0, 0}, cU11 = {0, 0, 0, 0};
    f4_t cW0 = {0, 0, 0, 0}, cW1 = {0, 0, 0, 0}, cG0 = {0, 0, 0, 0}, cG1 = {0, 0, 0, 0};
    {
      const unsigned short* hb = L.hnA;
      const unsigned short* xb = &L.xtA[0][0];
      const int r1 = 16 + (l15 < 4 ? l15 : 3);  // rows 20..31 duplicate row 19 (ignored)
#pragma unroll
      for (int kf = 0; kf < 8; ++kf) {
        const int blk = (wv << 5) + (kf << 2) + lo4;  // 8-elem k-block index, 0..127
        const s8_t a0 = *(const s8_t*)&hb[(l15 << 10) + ((blk ^ l15) << 3)];
        const s8_t a1 = *(const s8_t*)&hb[(r1 << 10) + ((blk ^ (r1 & 15)) << 3)];
        const s8_t ax = *(const s8_t*)&xb[(l15 & 1) * 1024 + (blk << 3)];
        cU00 = MFMA(a0, BUh[0][kf], cU00);
        cU00 = MFMA(a0, BUl[0][kf], cU00);
        cU01 = MFMA(a0, BUh[1][kf], cU01);
        cU01 = MFMA(a0, BUl[1][kf], cU01);
        cU10 = MFMA(a1, BUh[0][kf], cU10);
        cU10 = MFMA(a1, BUl[0][kf], cU10);
        cU11 = MFMA(a1, BUh[1][kf], cU11);
        cU11 = MFMA(a1, BUl[1][kf], cU11);
        cW0 = MFMA(ax, BWh[0][kf], cW0);
        cW0 = MFMA(ax, BWl[0][kf], cW0);
        cW1 = MFMA(ax, BWh[1][kf], cW1);
        cW1 = MFMA(ax, BWl[1][kf], cW1);
        cG0 = MFMA(ax, a0, cG0);
        cG1 = MFMA(ax, a1, cG1);
      }
    }
#pragma unroll
    for (int q = 0; q < 4; ++q) {
      const int r = (lo4 << 2) + q;
      L.credU[wv][0][0][r][l15] = cU00[q];
      L.credU[wv][0][1][r][l15] = cU01[q];
      L.credU[wv][1][0][r][l15] = cU10[q];
      L.credU[wv][1][1][r][l15] = cU11[q];
    }
    if (lo4 == 0) {
      L.wxAcc[wv][0][l15] = cW0[0] + cW0[1];
      L.wxAcc[wv][1][l15] = cW1[0] + cW1[1];
      L.gAcc[wv][0][l15] = cG0[0] + cG0[1];
      L.gAcc[wv][1][l15] = cG1[0] + cG1[1];
    }
    bar_lds();  // S1 — the ONLY block barrier in the phase

    // xt^{t+1}: wave-local write, no reader until next MFMA; off the poll path
    if (t + 1 < S) build_xt(&L.xtA[0][0], tid, evv + mvv);

    // ---- update + publish ----
    if (tid < 160) {
      const int i = tid >> 3, c4 = (tid & 7) << 2;
      const int mt = i >> 4, r = i & 15, nt = c4 >> 4, ccc = c4 & 15;
      const f4_t sU = *(const f4_t*)&L.credU[0][mt][nt][r][ccc] +
                      *(const f4_t*)&L.credU[1][mt][nt][r][ccc] +
                      *(const f4_t*)&L.credU[2][mt][nt][r][ccc] +
                      *(const f4_t*)&L.credU[3][mt][nt][r][ccc];
      const f4_t wx = *(const f4_t*)&L.wxAcc[0][nt][ccc] +
                      *(const f4_t*)&L.wxAcc[1][nt][ccc] +
                      *(const f4_t*)&L.wxAcc[2][nt][ccc] +
                      *(const f4_t*)&L.wxAcc[3][nt][ccc];
      const f4_t kv = *(const f4_t*)&L.KVs[i][c4];
      const f4_t oh = *(const f4_t*)&L.ownH[i][c4];
      const float s = sreg;
      const float gpre = s * (L.gAcc[0][mt][r] + L.gAcc[1][mt][r] +
                              L.gAcc[2][mt][r] + L.gAcc[3][mt][r]) + kxreg;
      const float g = sigm_fast(gpre);
      f4_t hn;
      float sq = 0.f;
#pragma unroll
      for (int u = 0; u < 4; ++u) {
        const float cand = tanh_fast(s * sU[u] + kv[u] + wx[u]);
        const float hx = s * oh[u] + g * cand;
        hn[u] = hx;
        sq += hx * hx;
      }
      *(f4_t*)&L.ownH[i][c4] = hn;
      const unsigned d0 = (unsigned)f2bf(hn[0]) | ((unsigned)f2bf(hn[1]) << 16);
      const unsigned d1 = (unsigned)f2bf(hn[2]) | ((unsigned)f2bf(hn[3]) << 16);
      u64_t* hb8 = (u64_t*)Hbuf + (size_t)(nxt2 * B + b) * (NB * 256) +
                   (i << 8) + (wg << 3) + (c4 >> 2);
      ASTORE64(hb8, (u64_t)d0 | ((u64_t)d1 << 32));
      sq += __shfl_xor(sq, 1);
      sq += __shfl_xor(sq, 2);
      sq += __shfl_xor(sq, 4);
      if ((tid & 7) == 0) {
        unsigned* np = (unsigned*)NormP + ((size_t)(nxt2 * B + b) * NB + i) * NWG + wg;
        ASTORE32(np, __float_as_uint(sq));
      }
    }

    // ---- per-wave release: drain OWN stores (vmcnt is per-wave), set slot ----
    if (wv < 3) {
      asm volatile("s_waitcnt vmcnt(0)" ::: "memory");
      if (ln == 0) ASTORE32(ctrp + (wg << 2) + wv, (unsigned)(t + 1));
    }

    if (t + 1 < S) {
      poll96(ctrp, ln31, (unsigned)(t + 1));
      // ---- gather own h-chunk + NormP + KX ----
      u64_t hv[20];
      const u64_t* g0 = (const u64_t*)Hbuf + (size_t)(nxt2 * B + b) * (NB * 256);
#pragma unroll
      for (int j = 0; j < 20; ++j) hv[j] = ALOAD64(g0 + j * 256 + tid);
      float np0 = 0.f;
      if (tid < 160) {
        const int i = tid >> 3;
        const u64_t* n0 = (const u64_t*)NormP + ((size_t)(nxt2 * B + b) * NB + i) * 16 + ((tid & 7) << 1);
        const u64_t a0 = ALOAD64(n0);
        const u64_t a1 = ALOAD64(n0 + 1);
        np0 = u64lo(a0) + u64hi(a0) + u64lo(a1) + u64hi(a1);
        kxreg = KX[((size_t)b * S + t + 1) * NB + i];
      }
      stage_h(L.hnA, tid, hv);           // wave-local: own chunk only
      if (tid < 160) {
        float s0 = np0;
        s0 += __shfl_xor(s0, 1);
        s0 += __shfl_xor(s0, 2);
        s0 += __shfl_xor(s0, 4);
        sreg = rcp_f(sqrtf(s0) + EPS);
      }
      if (t + 2 < S) {
        evv = ((const f4_t*)e)[(size_t)(b * S + t + 2) * 256 + tid];
        mvv = ((const f4_t*)m)[(size_t)(b * S + t + 2) * 256 + tid];
      }
      // own-wave LDS staging visible to own-wave ds_reads next iteration
      asm volatile("s_waitcnt lgkmcnt(0)" ::: "memory");
    }
  }

  // ---- final: wait all slots at S, reduce NormP(parity 0), write out ----
  poll96(ctrp, ln31, (unsigned)S);
  if (tid < 160) {
    const int i = tid >> 3, c4 = (tid & 7) << 2;
    const u64_t* np8 = (const u64_t*)NormP + ((size_t)(0 * B + b) * NB + i) * 16 + ((tid & 7) << 1);
    const u64_t x0 = ALOAD64(np8);
    const u64_t x1 = ALOAD64(np8 + 1);
    float sq = u64lo(x0) + u64hi(x0) + u64lo(x1) + u64hi(x1);
    sq += __shfl_xor(sq, 1);
    sq += __shfl_xor(sq, 2);
    sq += __shfl_xor(sq, 4);
    const float sc = rcp_f(sqrtf(sq) + EPS);
    const f4_t oh = *(const f4_t*)&L.ownH[i][c4];
    f4_t ov;
#pragma unroll
    for (int u = 0; u < 4; ++u) ov[u] = sc * oh[u];
    *(f4_t*)(out + (size_t)b * NB * D + (size_t)i * D + (wg << 5) + c4) = ov;
  }
}

}  // namespace

extern "C" void kernel_launch(void* const* d_in, const int* in_sizes, int n_in,
                              void* d_out, int out_size, void* d_ws, size_t ws_size,
                              hipStream_t stream) {
  const float* e = (const float*)d_in[0];
  const float* m = (const float*)d_in[1];
  const float* state = (const float*)d_in[2];
  const float* U = (const float*)d_in[3];
  const float* V = (const float*)d_in[4];
  const float* W = (const float*)d_in[5];
  const float* keys = (const float*)d_in[6];
  float* out = (float*)d_out;
  char* ws = (char*)d_ws;

  unsigned* Hbuf = (unsigned*)(ws + OFF_HBUF);
  float* NormP = (float*)(ws + OFF_NORM);
  int* ctr = (int*)(ws + OFF_CTR);
  float* KV = (float*)(ws + OFF_KV);
  float* KX = (float*)(ws + OFF_KX);
  unsigned short* Uhi = (unsigned short*)(ws + OFF_UHI);
  unsigned short* Ulo = (unsigned short*)(ws + OFF_ULO);
  unsigned short* Whi = (unsigned short*)(ws + OFF_WHI);
  unsigned short* Wlo = (unsigned short*)(ws + OFF_WLO);

  k_convert<<<512, 256, 0, stream>>>(U, W, Uhi, Ulo, Whi, Wlo);
  k_kv<<<16, 256, 0, stream>>>(keys, V, KV);
  k_kx<<<B * S, 256, 0, stream>>>(e, m, keys, KX);
  k_state<<<344, 256, 0, stream>>>(state, Hbuf, NormP, ctr);
  k_rnn<<<B * NWG, 256, 0, stream>>>(e, m, state, KX, KV, Uhi, Ulo, Whi, Wlo,
                                     Hbuf, NormP, ctr, out);
}

// Round 6
// 14962.358 us; speedup vs baseline: 1.5101x; 1.5101x over previous
//
#include <hip/hip_runtime.h>
#include <cstdint>
#include <cstddef>

namespace {

constexpr int D   = 1024;
constexpr int NB  = 20;
constexpr int B   = 8;
constexpr int S   = 2048;
constexpr int NWG = 32;      // workgroups cooperating per batch
constexpr float EPS = 1e-8f;

typedef __attribute__((ext_vector_type(4))) float f4_t;
typedef __attribute__((ext_vector_type(8))) short s8_t;
typedef unsigned long long u64_t;

__device__ __forceinline__ unsigned short f2bf(float f) {
  unsigned u = __float_as_uint(f);
  u += 0x7fffu + ((u >> 16) & 1u);     // RNE
  return (unsigned short)(u >> 16);
}
__device__ __forceinline__ float bf2f(unsigned short h) {
  return __uint_as_float(((unsigned)h) << 16);
}
__device__ __forceinline__ float u64lo(u64_t x) { return __uint_as_float((unsigned)x); }
__device__ __forceinline__ float u64hi(u64_t x) { return __uint_as_float((unsigned)(x >> 32)); }
__device__ __forceinline__ float rcp_f(float x) { return __builtin_amdgcn_rcpf(x); }
__device__ __forceinline__ float sigm_fast(float x) { return rcp_f(1.0f + __expf(-x)); }
__device__ __forceinline__ float tanh_fast(float x) {
  const float e = __expf(2.0f * x);
  return 1.0f - 2.0f * rcp_f(e + 1.0f);
}

#define MFMA(a, b, c) __builtin_amdgcn_mfma_f32_16x16x32_bf16((a), (b), (c), 0, 0, 0)
#define ALOAD64(p) __hip_atomic_load((p), __ATOMIC_RELAXED, __HIP_MEMORY_SCOPE_AGENT)
#define ASTORE64(p, v) __hip_atomic_store((p), (v), __ATOMIC_RELAXED, __HIP_MEMORY_SCOPE_AGENT)
#define ALOAD32(p) __hip_atomic_load((p), __ATOMIC_RELAXED, __HIP_MEMORY_SCOPE_AGENT)
#define ASTORE32(p, v) __hip_atomic_store((p), (v), __ATOMIC_RELAXED, __HIP_MEMORY_SCOPE_AGENT)

// ---- workspace layout (bytes) ----
constexpr size_t OFF_HBUF = 0;                                   // u32 [2][B][NB][512]  (bf16 pairs)
constexpr size_t OFF_NORM = OFF_HBUF + 2ull * B * NB * 512 * 4;  // f32 [2][B][NB][NWG]
constexpr size_t OFF_CTR  = OFF_NORM + 2ull * B * NB * NWG * 4;  // u32 [B][32] per-block step flags
constexpr size_t OFF_KV   = OFF_CTR + (size_t)B * 32 * 4;        // f32 [NB][D]
constexpr size_t OFF_KX   = OFF_KV + (size_t)NB * D * 4;         // f32 [B*S][NB]
constexpr size_t OFF_UHI  = OFF_KX + (size_t)B * S * NB * 4;     // u16 [D][D]
constexpr size_t OFF_ULO  = OFF_UHI + (size_t)D * D * 2;
constexpr size_t OFF_WHI  = OFF_ULO + (size_t)D * D * 2;
constexpr size_t OFF_WLO  = OFF_WHI + (size_t)D * D * 2;

// ---------------- init kernels ----------------

__global__ void k_convert(const float* __restrict__ U, const float* __restrict__ W,
                          unsigned short* __restrict__ Uhi, unsigned short* __restrict__ Ulo,
                          unsigned short* __restrict__ Whi, unsigned short* __restrict__ Wlo) {
  const int n = D * D;
  for (int i = blockIdx.x * blockDim.x + threadIdx.x; i < n; i += gridDim.x * blockDim.x) {
    float u = U[i];
    unsigned short h = f2bf(u);
    Uhi[i] = h;
    Ulo[i] = f2bf(u - bf2f(h));
    float w = W[i];
    h = f2bf(w);
    Whi[i] = h;
    Wlo[i] = f2bf(w - bf2f(h));
  }
}

// KV[i][j] = keys[i] . V[j]
__global__ void k_kv(const float* __restrict__ keys, const float* __restrict__ V,
                     float* __restrict__ KV) {
  const int tid = threadIdx.x;
  const int j = blockIdx.x * 64 + (tid >> 2);
  const int kq = tid & 3;
  const f4_t* v4 = (const f4_t*)(V + (size_t)j * D + kq * 256);
  const f4_t* k4base = (const f4_t*)keys;
  float acc[NB];
#pragma unroll
  for (int i = 0; i < NB; ++i) acc[i] = 0.f;
  for (int q = 0; q < 64; ++q) {
    const f4_t v = v4[q];
#pragma unroll
    for (int i = 0; i < NB; ++i) {
      const f4_t kk = k4base[i * 256 + kq * 64 + q];
      acc[i] += kk[0] * v[0] + kk[1] * v[1] + kk[2] * v[2] + kk[3] * v[3];
    }
  }
#pragma unroll
  for (int i = 0; i < NB; ++i) {
    float s = acc[i];
    s += __shfl_xor(s, 1);
    s += __shfl_xor(s, 2);
    if (kq == 0) KV[(size_t)i * D + j] = s;
  }
}

// KX[bt][i] = keys[i] . (e[bt]+m[bt])
__global__ void k_kx(const float* __restrict__ e, const float* __restrict__ m,
                     const float* __restrict__ keys, float* __restrict__ KX) {
  __shared__ f4_t xs[256];
  __shared__ float part[NB][8];
  const int bt = blockIdx.x, tid = threadIdx.x;
  xs[tid] = ((const f4_t*)e)[(size_t)bt * 256 + tid] + ((const f4_t*)m)[(size_t)bt * 256 + tid];
  __syncthreads();
  if (tid < 160) {
    const int i = tid >> 3, s8 = tid & 7;
    float acc = 0.f;
    const f4_t* k4 = (const f4_t*)keys + i * 256 + s8 * 32;
    for (int q = 0; q < 32; ++q) {
      const f4_t kk = k4[q];
      const f4_t xx = xs[s8 * 32 + q];
      acc += kk[0] * xx[0] + kk[1] * xx[1] + kk[2] * xx[2] + kk[3] * xx[3];
    }
    part[i][s8] = acc;
  }
  __syncthreads();
  if (tid < NB) {
    float s = 0.f;
#pragma unroll
    for (int q = 0; q < 8; ++q) s += part[tid][q];
    KX[(size_t)bt * NB + tid] = s;
  }
}

__global__ void k_state(const float* __restrict__ state, unsigned* __restrict__ Hbuf,
                        float* __restrict__ NormP, int* __restrict__ ctr) {
  const int idx = blockIdx.x * 256 + threadIdx.x;
  if (idx < B * NB * 512) {
    const int r = idx % (NB * 512);
    const int i = r >> 9, d2 = (r & 511) << 1;
    const unsigned short a = f2bf(state[i * D + d2]);
    const unsigned short c = f2bf(state[i * D + d2 + 1]);
    Hbuf[idx] = (unsigned)a | ((unsigned)c << 16);
  }
  const int j = idx - B * NB * 512;
  if (j >= 0 && j < B * NB * NWG) NormP[j] = 1.0f / 32.0f;  // sumsq=1 -> s=1 exactly
  const int q = idx - B * NB * 512 - B * NB * NWG;
  if (q >= 0 && q < B * 32) ctr[q] = 0;
}

// ---------------- persistent recurrence kernel ----------------
// Round-3 structure (the session best, 11.9ms) + XCD-local batch mapping
// (the one counter-proven independent win from round 4: FETCH 3.34GB->0.47GB).
// 256 blocks x 256 threads (4 waves). Block = batch x column-slice-of-32.
//   * batch = blockIdx & 7 -> all 32 blocks of a batch land on ONE XCD
//     (round-robin dispatch heuristic, perf-only): the 32x-redundant e/m row
//     reads are served from that XCD's L2 instead of thrashing HBM/LLC, and
//     the exchange (Hbuf/NormP/flags, all batch-local) stays XCD-local too.
//   * Protocol per phase t (unchanged from round 3 — rounds 4/5 proved both
//     deviations regress: 8-wave split = issue-bound 2x; per-wave flags =
//     LLC line ping-pong 2x):
//     MFMA -> S1 (lds barrier) -> update+publish -> S3 (full drain)
//     flag := t+1 -> poll 32 same-batch flags >= t+1
//     gather h^{t+1}/NormP, build xt^{t+1}, stage -> S2 (lds barrier)
// Parity-reuse safety: flag >= t+1 implies that block finished gathering
// h^t (parity t&1); a writer of h^{t+2} (same parity) polls >= t+1 before
// its update, so no overwrite race.

struct __align__(16) LdsT {
  unsigned short hnA[NB * 1024];    // raw bf16 h, swizzled               (40 KB)
  unsigned short xtA[2][1024];      // xt hi/lo rows                       (4 KB)
  float credU[4][2][2][16][20];     // [wv][mt][nt][row][col pad20]       (20 KB)
  float wxAcc[4][2][16];            // [wv][nt][col]
  float gAcc[4][2][16];             // [wv][mt][col]
  float KVs[NB][32];
  float ownH[NB][32];               // fp32 unnormalized h slice
  float pad_force_1_block_per_cu[3072];  // lift LDS >80KB so 2 blocks never share a CU
};

__device__ __forceinline__ void build_xt(unsigned short* xt /* [2][1024] */, int tid, f4_t x) {
  const unsigned short h0 = f2bf(x[0]), h1 = f2bf(x[1]), h2 = f2bf(x[2]), h3 = f2bf(x[3]);
  const unsigned short u0 = f2bf(x[0] - bf2f(h0)), u1 = f2bf(x[1] - bf2f(h1));
  const unsigned short u2 = f2bf(x[2] - bf2f(h2)), u3 = f2bf(x[3] - bf2f(h3));
  const int kp = tid << 2;
  *(unsigned*)&xt[kp] = (unsigned)h0 | ((unsigned)h1 << 16);
  *(unsigned*)&xt[kp + 2] = (unsigned)h2 | ((unsigned)h3 << 16);
  *(unsigned*)&xt[1024 + kp] = (unsigned)u0 | ((unsigned)u1 << 16);
  *(unsigned*)&xt[1024 + kp + 2] = (unsigned)u2 | ((unsigned)u3 << 16);
}

__device__ __forceinline__ void stage_h(unsigned short* hn, int tid, const u64_t* hv) {
  const int blkk = tid >> 1;
  const int half = (tid & 1) << 2;
#pragma unroll
  for (int j = 0; j < 20; ++j)
    *(u64_t*)&hn[(j << 10) + ((blkk ^ (j & 15)) << 3) + half] = hv[j];
}

// lds-only barrier: LDS writes visible, VMEM ops stay in flight across it.
__device__ __forceinline__ void bar_lds() {
  asm volatile("s_waitcnt lgkmcnt(0)\n\ts_barrier" ::: "memory");
}
// full barrier: all LDS + VMEM (incl. agent-scope publish stores) drained.
__device__ __forceinline__ void bar_full() {
  asm volatile("s_waitcnt vmcnt(0) lgkmcnt(0)\n\ts_barrier" ::: "memory");
}

// poll until all 32 per-block flags reach tgt; own slot (wg) substituted since
// our flag store precedes this call in program order. pv = pre-issued first read.
__device__ __forceinline__ void poll32(const unsigned* fb, int ln31, int wg,
                                       unsigned tgt, unsigned pv) {
  if (__ballot(pv >= tgt) == ~0ull) return;
  for (;;) {
    const unsigned v = (ln31 == wg) ? tgt : ALOAD32(fb + ln31);
    if (__ballot(v >= tgt) == ~0ull) return;
    __builtin_amdgcn_s_sleep(1);
  }
}

__launch_bounds__(256, 1)
__global__ void k_rnn(const float* __restrict__ e, const float* __restrict__ m,
                      const float* __restrict__ state,
                      const float* __restrict__ KX, const float* __restrict__ KV,
                      const unsigned short* __restrict__ Uhi, const unsigned short* __restrict__ Ulo,
                      const unsigned short* __restrict__ Whi, const unsigned short* __restrict__ Wlo,
                      unsigned* __restrict__ Hbuf, float* __restrict__ NormP,
                      int* __restrict__ ctr, float* __restrict__ out) {
  __shared__ LdsT L;
  const int tid = threadIdx.x;
  const int b = blockIdx.x & 7;                   // batch 0..7 == XCD (heuristic)
  const int wg = blockIdx.x >> 3;                 // column slice 0..31
  const int wv = tid >> 6;
  const int ln = tid & 63;
  const int l15 = ln & 15;
  const int lo4 = ln >> 4;
  const int ln31 = tid & 31;
  unsigned* ctrp = (unsigned*)ctr + b * 32;

  // resident B-fragments: U and W column slices, bf16 hi/lo, this wave's k-chunk.
  s8_t BUh[2][8], BUl[2][8], BWh[2][8], BWl[2][8];
  {
    const int rowb = (wg << 5) + l15;
#pragma unroll
    for (int nt = 0; nt < 2; ++nt)
#pragma unroll
      for (int kf = 0; kf < 8; ++kf) {
        const size_t off = (size_t)(rowb + nt * 16) * D + (wv << 8) + (kf << 5) + (lo4 << 3);
        BUh[nt][kf] = *(const s8_t*)(Uhi + off);
        BUl[nt][kf] = *(const s8_t*)(Ulo + off);
        BWh[nt][kf] = *(const s8_t*)(Whi + off);
        BWl[nt][kf] = *(const s8_t*)(Wlo + off);
      }
  }
  if (tid < 160) {
    const int i = tid >> 3, c4 = (tid & 7) << 2;
    *(f4_t*)&L.ownH[i][c4] = *(const f4_t*)(state + (size_t)i * D + (wg << 5) + c4);
    *(f4_t*)&L.KVs[i][c4] = *(const f4_t*)(KV + (size_t)i * D + (wg << 5) + c4);
  }

  f4_t evv, mvv;
  float sreg = 1.f;   // exact: initial state pre-normalized (NormP=1/32)
  float kxreg = 0.f;

  // ---- bootstrap: stage step 0 ----
  {
    u64_t hv[20];
    const u64_t* hb8 = (const u64_t*)Hbuf + (size_t)(0 * B + b) * (NB * 256);
#pragma unroll
    for (int j = 0; j < 20; ++j) hv[j] = ALOAD64(hb8 + j * 256 + tid);
    const f4_t x0 = ((const f4_t*)e)[(size_t)(b * S) * 256 + tid] +
                    ((const f4_t*)m)[(size_t)(b * S) * 256 + tid];
    build_xt(&L.xtA[0][0], tid, x0);
    stage_h(L.hnA, tid, hv);
    if (tid < 160) kxreg = KX[(size_t)(b * S) * NB + (tid >> 3)];
    evv = ((const f4_t*)e)[(size_t)(b * S + 1) * 256 + tid];
    mvv = ((const f4_t*)m)[(size_t)(b * S + 1) * 256 + tid];
  }
  __syncthreads();

  for (int t = 0; t < S; ++t) {
    const int nxt2 = (t + 1) & 1;

    // ---- MFMA: h@U^T (hi/lo), x@W^T (hi/lo), x.h gate ----
    f4_t cU00 = {0, 0, 0, 0}, cU01 = {0, 0, 0, 0}, cU10 = {0, 0, 0, 0}, cU11 = {0, 0, 0, 0};
    f4_t cW0 = {0, 0, 0, 0}, cW1 = {0, 0, 0, 0}, cG0 = {0, 0, 0, 0}, cG1 = {0, 0, 0, 0};
    {
      const unsigned short* hb = L.hnA;
      const unsigned short* xb = &L.xtA[0][0];
      const int r1 = 16 + (l15 < 4 ? l15 : 3);  // rows 20..31 duplicate row 19 (ignored)
#pragma unroll
      for (int kf = 0; kf < 8; ++kf) {
        const int blk = (wv << 5) + (kf << 2) + lo4;  // 8-elem k-block index, 0..127
        const s8_t a0 = *(const s8_t*)&hb[(l15 << 10) + ((blk ^ l15) << 3)];
        const s8_t a1 = *(const s8_t*)&hb[(r1 << 10) + ((blk ^ (r1 & 15)) << 3)];
        const s8_t ax = *(const s8_t*)&xb[(l15 & 1) * 1024 + (blk << 3)];
        cU00 = MFMA(a0, BUh[0][kf], cU00);
        cU00 = MFMA(a0, BUl[0][kf], cU00);
        cU01 = MFMA(a0, BUh[1][kf], cU01);
        cU01 = MFMA(a0, BUl[1][kf], cU01);
        cU10 = MFMA(a1, BUh[0][kf], cU10);
        cU10 = MFMA(a1, BUl[0][kf], cU10);
        cU11 = MFMA(a1, BUh[1][kf], cU11);
        cU11 = MFMA(a1, BUl[1][kf], cU11);
        cW0 = MFMA(ax, BWh[0][kf], cW0);
        cW0 = MFMA(ax, BWl[0][kf], cW0);
        cW1 = MFMA(ax, BWh[1][kf], cW1);
        cW1 = MFMA(ax, BWl[1][kf], cW1);
        cG0 = MFMA(ax, a0, cG0);
        cG1 = MFMA(ax, a1, cG1);
      }
    }
#pragma unroll
    for (int q = 0; q < 4; ++q) {
      const int r = (lo4 << 2) + q;
      L.credU[wv][0][0][r][l15] = cU00[q];
      L.credU[wv][0][1][r][l15] = cU01[q];
      L.credU[wv][1][0][r][l15] = cU10[q];
      L.credU[wv][1][1][r][l15] = cU11[q];
    }
    if (lo4 == 0) {
      L.wxAcc[wv][0][l15] = cW0[0] + cW0[1];
      L.wxAcc[wv][1][l15] = cW1[0] + cW1[1];
      L.gAcc[wv][0][l15] = cG0[0] + cG0[1];
      L.gAcc[wv][1][l15] = cG1[0] + cG1[1];
    }
    bar_lds();  // S1: credU/wx/g visible

    // pre-issue partner-flag read (resolves during update; hits when partners ahead)
    unsigned pv = 0;
    if (t + 1 < S) pv = (ln31 == wg) ? (unsigned)(t + 1) : ALOAD32(ctrp + ln31);

    // ---- update + publish ----
    if (tid < 160) {
      const int i = tid >> 3, c4 = (tid & 7) << 2;
      const int mt = i >> 4, r = i & 15, nt = c4 >> 4, ccc = c4 & 15;
      const f4_t sU = *(const f4_t*)&L.credU[0][mt][nt][r][ccc] +
                      *(const f4_t*)&L.credU[1][mt][nt][r][ccc] +
                      *(const f4_t*)&L.credU[2][mt][nt][r][ccc] +
                      *(const f4_t*)&L.credU[3][mt][nt][r][ccc];
      const f4_t wx = *(const f4_t*)&L.wxAcc[0][nt][ccc] +
                      *(const f4_t*)&L.wxAcc[1][nt][ccc] +
                      *(const f4_t*)&L.wxAcc[2][nt][ccc] +
                      *(const f4_t*)&L.wxAcc[3][nt][ccc];
      const f4_t kv = *(const f4_t*)&L.KVs[i][c4];
      const f4_t oh = *(const f4_t*)&L.ownH[i][c4];
      const float s = sreg;
      const float gpre = s * (L.gAcc[0][mt][r] + L.gAcc[1][mt][r] +
                              L.gAcc[2][mt][r] + L.gAcc[3][mt][r]) + kxreg;
      const float g = sigm_fast(gpre);
      f4_t hn;
      float sq = 0.f;
#pragma unroll
      for (int u = 0; u < 4; ++u) {
        const float cand = tanh_fast(s * sU[u] + kv[u] + wx[u]);
        const float hx = s * oh[u] + g * cand;
        hn[u] = hx;
        sq += hx * hx;
      }
      *(f4_t*)&L.ownH[i][c4] = hn;
      const unsigned d0 = (unsigned)f2bf(hn[0]) | ((unsigned)f2bf(hn[1]) << 16);
      const unsigned d1 = (unsigned)f2bf(hn[2]) | ((unsigned)f2bf(hn[3]) << 16);
      u64_t* hb8 = (u64_t*)Hbuf + (size_t)(nxt2 * B + b) * (NB * 256) +
                   (i << 8) + (wg << 3) + (c4 >> 2);
      ASTORE64(hb8, (u64_t)d0 | ((u64_t)d1 << 32));
      sq += __shfl_xor(sq, 1);
      sq += __shfl_xor(sq, 2);
      sq += __shfl_xor(sq, 4);
      if ((tid & 7) == 0) {
        unsigned* np = (unsigned*)NormP + ((size_t)(nxt2 * B + b) * NB + i) * NWG + wg;
        ASTORE32(np, __float_as_uint(sq));
      }
    }
    bar_full();  // S3: publish drained across all waves

    if (tid == 0) ASTORE32(ctrp + wg, (unsigned)(t + 1));

    if (t + 1 < S) {
      poll32(ctrp, ln31, wg, (unsigned)(t + 1), pv);
      // ---- gather h^{t+1} + NormP + KX, one burst ----
      u64_t hv[20];
      const u64_t* g0 = (const u64_t*)Hbuf + (size_t)(nxt2 * B + b) * (NB * 256);
#pragma unroll
      for (int j = 0; j < 20; ++j) hv[j] = ALOAD64(g0 + j * 256 + tid);
      float np0 = 0.f;
      if (tid < 160) {
        const int i = tid >> 3;
        const u64_t* n0 = (const u64_t*)NormP + ((size_t)(nxt2 * B + b) * NB + i) * 16 + ((tid & 7) << 1);
        const u64_t a0 = ALOAD64(n0);
        const u64_t a1 = ALOAD64(n0 + 1);
        np0 = u64lo(a0) + u64hi(a0) + u64lo(a1) + u64hi(a1);
        kxreg = KX[((size_t)b * S + t + 1) * NB + i];
      }
      // xt^{t+1} from prefetched regs; overlaps gather flight
      build_xt(&L.xtA[0][0], tid, evv + mvv);
      if (t + 2 < S) {
        evv = ((const f4_t*)e)[(size_t)(b * S + t + 2) * 256 + tid];
        mvv = ((const f4_t*)m)[(size_t)(b * S + t + 2) * 256 + tid];
      }
      stage_h(L.hnA, tid, hv);
      if (tid < 160) {
        float s0 = np0;
        s0 += __shfl_xor(s0, 1);
        s0 += __shfl_xor(s0, 2);
        s0 += __shfl_xor(s0, 4);
        sreg = rcp_f(sqrtf(s0) + EPS);
      }
    }
    bar_lds();  // S2: staged hnA/xtA visible for next phase
  }

  // ---- final: wait all flags at S, reduce NormP(parity 0), write out ----
  poll32(ctrp, ln31, wg, (unsigned)S, 0u);
  if (tid < 160) {
    const int i = tid >> 3, c4 = (tid & 7) << 2;
    const u64_t* np8 = (const u64_t*)NormP + ((size_t)(0 * B + b) * NB + i) * 16 + ((tid & 7) << 1);
    const u64_t x0 = ALOAD64(np8);
    const u64_t x1 = ALOAD64(np8 + 1);
    float sq = u64lo(x0) + u64hi(x0) + u64lo(x1) + u64hi(x1);
    sq += __shfl_xor(sq, 1);
    sq += __shfl_xor(sq, 2);
    sq += __shfl_xor(sq, 4);
    const float sc = rcp_f(sqrtf(sq) + EPS);
    const f4_t oh = *(const f4_t*)&L.ownH[i][c4];
    f4_t ov;
#pragma unroll
    for (int u = 0; u < 4; ++u) ov[u] = sc * oh[u];
    *(f4_t*)(out + (size_t)b * NB * D + (size_t)i * D + (wg << 5) + c4) = ov;
  }
}

}  // namespace

extern "C" void kernel_launch(void* const* d_in, const int* in_sizes, int n_in,
                              void* d_out, int out_size, void* d_ws, size_t ws_size,
                              hipStream_t stream) {
  const float* e = (const float*)d_in[0];
  const float* m = (const float*)d_in[1];
  const float* state = (const float*)d_in[2];
  const float* U = (const float*)d_in[3];
  const float* V = (const float*)d_in[4];
  const float* W = (const float*)d_in[5];
  const float* keys = (const float*)d_in[6];
  float* out = (float*)d_out;
  char* ws = (char*)d_ws;

  unsigned* Hbuf = (unsigned*)(ws + OFF_HBUF);
  float* NormP = (float*)(ws + OFF_NORM);
  int* ctr = (int*)(ws + OFF_CTR);
  float* KV = (float*)(ws + OFF_KV);
  float* KX = (float*)(ws + OFF_KX);
  unsigned short* Uhi = (unsigned short*)(ws + OFF_UHI);
  unsigned short* Ulo = (unsigned short*)(ws + OFF_ULO);
  unsigned short* Whi = (unsigned short*)(ws + OFF_WHI);
  unsigned short* Wlo = (unsigned short*)(ws + OFF_WLO);

  k_convert<<<512, 256, 0, stream>>>(U, W, Uhi, Ulo, Whi, Wlo);
  k_kv<<<16, 256, 0, stream>>>(keys, V, KV);
  k_kx<<<B * S, 256, 0, stream>>>(e, m, keys, KX);
  k_state<<<342, 256, 0, stream>>>(state, Hbuf, NormP, ctr);
  k_rnn<<<B * NWG, 256, 0, stream>>>(e, m, state, KX, KV, Uhi, Ulo, Whi, Wlo,
                                     Hbuf, NormP, ctr, out);
}

// Round 7
// 11666.356 us; speedup vs baseline: 1.9367x; 1.2825x over previous
//
#include <hip/hip_runtime.h>
#include <cstdint>
#include <cstddef>

namespace {

constexpr int D   = 1024;
constexpr int NB  = 20;
constexpr int B   = 8;
constexpr int S   = 2048;
constexpr int NWG = 32;      // workgroups cooperating per batch
constexpr float EPS = 1e-8f;

typedef __attribute__((ext_vector_type(4))) float f4_t;
typedef __attribute__((ext_vector_type(8))) short s8_t;
typedef unsigned long long u64_t;

__device__ __forceinline__ unsigned short f2bf(float f) {
  unsigned u = __float_as_uint(f);
  u += 0x7fffu + ((u >> 16) & 1u);     // RNE
  return (unsigned short)(u >> 16);
}
__device__ __forceinline__ float bf2f(unsigned short h) {
  return __uint_as_float(((unsigned)h) << 16);
}
__device__ __forceinline__ float u64lo(u64_t x) { return __uint_as_float((unsigned)x); }
__device__ __forceinline__ float u64hi(u64_t x) { return __uint_as_float((unsigned)(x >> 32)); }
__device__ __forceinline__ float rcp_f(float x) { return __builtin_amdgcn_rcpf(x); }
__device__ __forceinline__ float sigm_fast(float x) { return rcp_f(1.0f + __expf(-x)); }
__device__ __forceinline__ float tanh_fast(float x) {
  const float e = __expf(2.0f * x);
  return 1.0f - 2.0f * rcp_f(e + 1.0f);
}

#define MFMA(a, b, c) __builtin_amdgcn_mfma_f32_16x16x32_bf16((a), (b), (c), 0, 0, 0)
#define ALOAD64(p) __hip_atomic_load((p), __ATOMIC_RELAXED, __HIP_MEMORY_SCOPE_AGENT)
#define ASTORE64(p, v) __hip_atomic_store((p), (v), __ATOMIC_RELAXED, __HIP_MEMORY_SCOPE_AGENT)
#define ALOAD32(p) __hip_atomic_load((p), __ATOMIC_RELAXED, __HIP_MEMORY_SCOPE_AGENT)
#define ASTORE32(p, v) __hip_atomic_store((p), (v), __ATOMIC_RELAXED, __HIP_MEMORY_SCOPE_AGENT)

// ---- workspace layout (bytes) ----
constexpr size_t OFF_HBUF = 0;                                   // u32 [2][B][NB][512]  (bf16 pairs)
constexpr size_t OFF_NORM = OFF_HBUF + 2ull * B * NB * 512 * 4;  // f32 [2][B][NB][NWG]
constexpr size_t OFF_CTR  = OFF_NORM + 2ull * B * NB * NWG * 4;  // u32 [B][32] per-block step flags
constexpr size_t OFF_KV   = OFF_CTR + (size_t)B * 32 * 4;        // f32 [NB][D]
constexpr size_t OFF_KX   = OFF_KV + (size_t)NB * D * 4;         // f32 [B*S][NB]
constexpr size_t OFF_UHI  = OFF_KX + (size_t)B * S * NB * 4;     // u16 [D][D]
constexpr size_t OFF_ULO  = OFF_UHI + (size_t)D * D * 2;
constexpr size_t OFF_WHI  = OFF_ULO + (size_t)D * D * 2;
constexpr size_t OFF_WLO  = OFF_WHI + (size_t)D * D * 2;

// ---------------- init kernels ----------------

__global__ void k_convert(const float* __restrict__ U, const float* __restrict__ W,
                          unsigned short* __restrict__ Uhi, unsigned short* __restrict__ Ulo,
                          unsigned short* __restrict__ Whi, unsigned short* __restrict__ Wlo) {
  const int n = D * D;
  for (int i = blockIdx.x * blockDim.x + threadIdx.x; i < n; i += gridDim.x * blockDim.x) {
    float u = U[i];
    unsigned short h = f2bf(u);
    Uhi[i] = h;
    Ulo[i] = f2bf(u - bf2f(h));
    float w = W[i];
    h = f2bf(w);
    Whi[i] = h;
    Wlo[i] = f2bf(w - bf2f(h));
  }
}

// KV[i][j] = keys[i] . V[j]
__global__ void k_kv(const float* __restrict__ keys, const float* __restrict__ V,
                     float* __restrict__ KV) {
  const int tid = threadIdx.x;
  const int j = blockIdx.x * 64 + (tid >> 2);
  const int kq = tid & 3;
  const f4_t* v4 = (const f4_t*)(V + (size_t)j * D + kq * 256);
  const f4_t* k4base = (const f4_t*)keys;
  float acc[NB];
#pragma unroll
  for (int i = 0; i < NB; ++i) acc[i] = 0.f;
  for (int q = 0; q < 64; ++q) {
    const f4_t v = v4[q];
#pragma unroll
    for (int i = 0; i < NB; ++i) {
      const f4_t kk = k4base[i * 256 + kq * 64 + q];
      acc[i] += kk[0] * v[0] + kk[1] * v[1] + kk[2] * v[2] + kk[3] * v[3];
    }
  }
#pragma unroll
  for (int i = 0; i < NB; ++i) {
    float s = acc[i];
    s += __shfl_xor(s, 1);
    s += __shfl_xor(s, 2);
    if (kq == 0) KV[(size_t)i * D + j] = s;
  }
}

// KX[bt][i] = keys[i] . (e[bt]+m[bt])
__global__ void k_kx(const float* __restrict__ e, const float* __restrict__ m,
                     const float* __restrict__ keys, float* __restrict__ KX) {
  __shared__ f4_t xs[256];
  __shared__ float part[NB][8];
  const int bt = blockIdx.x, tid = threadIdx.x;
  xs[tid] = ((const f4_t*)e)[(size_t)bt * 256 + tid] + ((const f4_t*)m)[(size_t)bt * 256 + tid];
  __syncthreads();
  if (tid < 160) {
    const int i = tid >> 3, s8 = tid & 7;
    float acc = 0.f;
    const f4_t* k4 = (const f4_t*)keys + i * 256 + s8 * 32;
    for (int q = 0; q < 32; ++q) {
      const f4_t kk = k4[q];
      const f4_t xx = xs[s8 * 32 + q];
      acc += kk[0] * xx[0] + kk[1] * xx[1] + kk[2] * xx[2] + kk[3] * xx[3];
    }
    part[i][s8] = acc;
  }
  __syncthreads();
  if (tid < NB) {
    float s = 0.f;
#pragma unroll
    for (int q = 0; q < 8; ++q) s += part[tid][q];
    KX[(size_t)bt * NB + tid] = s;
  }
}

__global__ void k_state(const float* __restrict__ state, unsigned* __restrict__ Hbuf,
                        float* __restrict__ NormP, int* __restrict__ ctr) {
  const int idx = blockIdx.x * 256 + threadIdx.x;
  if (idx < B * NB * 512) {
    const int r = idx % (NB * 512);
    const int i = r >> 9, d2 = (r & 511) << 1;
    const unsigned short a = f2bf(state[i * D + d2]);
    const unsigned short c = f2bf(state[i * D + d2 + 1]);
    Hbuf[idx] = (unsigned)a | ((unsigned)c << 16);
  }
  const int j = idx - B * NB * 512;
  if (j >= 0 && j < B * NB * NWG) NormP[j] = 1.0f / 32.0f;  // sumsq=1 -> s=1 exactly
  const int q = idx - B * NB * 512 - B * NB * NWG;
  if (q >= 0 && q < B * 32) ctr[q] = 0;
}

// ---------------- persistent recurrence kernel ----------------
// Round-3 structure and mapping (session best, 11.9ms) + two compressions:
//   * b = blockIdx>>5 (SCATTERED batches). Round-5 proved XCD-local batches
//     regress 25%: 32 phase-locked blocks pulling the same 40KB Hbuf multicast
//     through ONE XCD<->LLC port serializes the exchange burst; scattering
//     spreads the same aggregate over 8 ports with phase-drifted batches.
//     (FETCH 3.3GB of e/m redundancy is harmless: 380GB/s, prefetched.)
//   * MFMA-section latency compaction: all 24 LDS fragment loads hoisted
//     ahead of a pure 112-MFMA burst (1 wave/SIMD exposes every ds_read->MFMA
//     dep ~120cy; grouped loads overlap their latency, MFMAs then stream).
//   * S2 barrier removed: staging is wave-local (stage_h writes blkk=tid>>1 =
//     exactly this wave's MFMA read range; build_xt likewise), so a per-wave
//     lgkmcnt(0) suffices. Cross-wave overwrite hazards (credU/hnA/xtA) are
//     gated by poll>=t+1, which transitively requires our own block's S3
//     (flag stored by tid0 only after the full-drain barrier). Block-level
//     flag protocol itself unchanged (round-4 proved per-wave flags regress).
// Per phase t:
//   MFMA -> S1 (lds barrier) -> update+publish -> S3 (full drain)
//   flag := t+1 -> poll 32 same-batch flags >= t+1
//   gather h^{t+1}/NormP, build xt^{t+1}, stage -> per-wave lgkmcnt(0)
// Parity-reuse safety: flag >= t+1 implies that block finished gathering
// h^t (parity t&1); a writer of h^{t+2} (same parity) polls >= t+1 before
// its update, so no overwrite race.

struct __align__(16) LdsT {
  unsigned short hnA[NB * 1024];    // raw bf16 h, swizzled               (40 KB)
  unsigned short xtA[2][1024];      // xt hi/lo rows                       (4 KB)
  float credU[4][2][2][16][20];     // [wv][mt][nt][row][col pad20]       (20 KB)
  float wxAcc[4][2][16];            // [wv][nt][col]
  float gAcc[4][2][16];             // [wv][mt][col]
  float KVs[NB][32];
  float ownH[NB][32];               // fp32 unnormalized h slice
  float pad_force_1_block_per_cu[3072];  // lift LDS >80KB so 2 blocks never share a CU
};

__device__ __forceinline__ void build_xt(unsigned short* xt /* [2][1024] */, int tid, f4_t x) {
  const unsigned short h0 = f2bf(x[0]), h1 = f2bf(x[1]), h2 = f2bf(x[2]), h3 = f2bf(x[3]);
  const unsigned short u0 = f2bf(x[0] - bf2f(h0)), u1 = f2bf(x[1] - bf2f(h1));
  const unsigned short u2 = f2bf(x[2] - bf2f(h2)), u3 = f2bf(x[3] - bf2f(h3));
  const int kp = tid << 2;
  *(unsigned*)&xt[kp] = (unsigned)h0 | ((unsigned)h1 << 16);
  *(unsigned*)&xt[kp + 2] = (unsigned)h2 | ((unsigned)h3 << 16);
  *(unsigned*)&xt[1024 + kp] = (unsigned)u0 | ((unsigned)u1 << 16);
  *(unsigned*)&xt[1024 + kp + 2] = (unsigned)u2 | ((unsigned)u3 << 16);
}

__device__ __forceinline__ void stage_h(unsigned short* hn, int tid, const u64_t* hv) {
  const int blkk = tid >> 1;
  const int half = (tid & 1) << 2;
#pragma unroll
  for (int j = 0; j < 20; ++j)
    *(u64_t*)&hn[(j << 10) + ((blkk ^ (j & 15)) << 3) + half] = hv[j];
}

// lds-only barrier: LDS writes visible, VMEM ops stay in flight across it.
__device__ __forceinline__ void bar_lds() {
  asm volatile("s_waitcnt lgkmcnt(0)\n\ts_barrier" ::: "memory");
}
// full barrier: all LDS + VMEM (incl. agent-scope publish stores) drained.
__device__ __forceinline__ void bar_full() {
  asm volatile("s_waitcnt vmcnt(0) lgkmcnt(0)\n\ts_barrier" ::: "memory");
}

// poll until all 32 per-block flags reach tgt; own slot (wg) substituted since
// our block's publishes are drained (S3) before any wave reaches this call.
// pv = pre-issued first read.
__device__ __forceinline__ void poll32(const unsigned* fb, int ln31, int wg,
                                       unsigned tgt, unsigned pv) {
  if (__ballot(pv >= tgt) == ~0ull) return;
  for (;;) {
    const unsigned v = (ln31 == wg) ? tgt : ALOAD32(fb + ln31);
    if (__ballot(v >= tgt) == ~0ull) return;
    __builtin_amdgcn_s_sleep(1);
  }
}

__launch_bounds__(256, 1)
__global__ void k_rnn(const float* __restrict__ e, const float* __restrict__ m,
                      const float* __restrict__ state,
                      const float* __restrict__ KX, const float* __restrict__ KV,
                      const unsigned short* __restrict__ Uhi, const unsigned short* __restrict__ Ulo,
                      const unsigned short* __restrict__ Whi, const unsigned short* __restrict__ Wlo,
                      unsigned* __restrict__ Hbuf, float* __restrict__ NormP,
                      int* __restrict__ ctr, float* __restrict__ out) {
  __shared__ LdsT L;
  const int tid = threadIdx.x;
  const int b = blockIdx.x >> 5;                  // batch 0..7 (scattered over XCDs)
  const int wg = blockIdx.x & 31;                 // column slice 0..31
  const int wv = tid >> 6;
  const int ln = tid & 63;
  const int l15 = ln & 15;
  const int lo4 = ln >> 4;
  const int ln31 = tid & 31;
  unsigned* ctrp = (unsigned*)ctr + b * 32;

  // resident B-fragments: U and W column slices, bf16 hi/lo, this wave's k-chunk.
  s8_t BUh[2][8], BUl[2][8], BWh[2][8], BWl[2][8];
  {
    const int rowb = (wg << 5) + l15;
#pragma unroll
    for (int nt = 0; nt < 2; ++nt)
#pragma unroll
      for (int kf = 0; kf < 8; ++kf) {
        const size_t off = (size_t)(rowb + nt * 16) * D + (wv << 8) + (kf << 5) + (lo4 << 3);
        BUh[nt][kf] = *(const s8_t*)(Uhi + off);
        BUl[nt][kf] = *(const s8_t*)(Ulo + off);
        BWh[nt][kf] = *(const s8_t*)(Whi + off);
        BWl[nt][kf] = *(const s8_t*)(Wlo + off);
      }
  }
  if (tid < 160) {
    const int i = tid >> 3, c4 = (tid & 7) << 2;
    *(f4_t*)&L.ownH[i][c4] = *(const f4_t*)(state + (size_t)i * D + (wg << 5) + c4);
    *(f4_t*)&L.KVs[i][c4] = *(const f4_t*)(KV + (size_t)i * D + (wg << 5) + c4);
  }

  f4_t evv, mvv;
  float sreg = 1.f;   // exact: initial state pre-normalized (NormP=1/32)
  float kxreg = 0.f;

  // ---- bootstrap: stage step 0 ----
  {
    u64_t hv[20];
    const u64_t* hb8 = (const u64_t*)Hbuf + (size_t)(0 * B + b) * (NB * 256);
#pragma unroll
    for (int j = 0; j < 20; ++j) hv[j] = ALOAD64(hb8 + j * 256 + tid);
    const f4_t x0 = ((const f4_t*)e)[(size_t)(b * S) * 256 + tid] +
                    ((const f4_t*)m)[(size_t)(b * S) * 256 + tid];
    build_xt(&L.xtA[0][0], tid, x0);
    stage_h(L.hnA, tid, hv);
    if (tid < 160) kxreg = KX[(size_t)(b * S) * NB + (tid >> 3)];
    evv = ((const f4_t*)e)[(size_t)(b * S + 1) * 256 + tid];
    mvv = ((const f4_t*)m)[(size_t)(b * S + 1) * 256 + tid];
  }
  __syncthreads();

  for (int t = 0; t < S; ++t) {
    const int nxt2 = (t + 1) & 1;

    // ---- MFMA: hoisted fragment loads, then pure MFMA burst ----
    f4_t cU00 = {0, 0, 0, 0}, cU01 = {0, 0, 0, 0}, cU10 = {0, 0, 0, 0}, cU11 = {0, 0, 0, 0};
    f4_t cW0 = {0, 0, 0, 0}, cW1 = {0, 0, 0, 0}, cG0 = {0, 0, 0, 0}, cG1 = {0, 0, 0, 0};
    {
      const unsigned short* hb = L.hnA;
      const unsigned short* xb = &L.xtA[0][0];
      const int r1 = 16 + (l15 < 4 ? l15 : 3);  // rows 20..31 duplicate row 19 (ignored)
      s8_t A0[8], A1[8], AX[8];
#pragma unroll
      for (int kf = 0; kf < 8; ++kf) {
        const int blk = (wv << 5) + (kf << 2) + lo4;  // 8-elem k-block index, 0..127
        A0[kf] = *(const s8_t*)&hb[(l15 << 10) + ((blk ^ l15) << 3)];
        A1[kf] = *(const s8_t*)&hb[(r1 << 10) + ((blk ^ (r1 & 15)) << 3)];
        AX[kf] = *(const s8_t*)&xb[(l15 & 1) * 1024 + (blk << 3)];
      }
#pragma unroll
      for (int kf = 0; kf < 8; ++kf) {
        cU00 = MFMA(A0[kf], BUh[0][kf], cU00);
        cU00 = MFMA(A0[kf], BUl[0][kf], cU00);
        cU01 = MFMA(A0[kf], BUh[1][kf], cU01);
        cU01 = MFMA(A0[kf], BUl[1][kf], cU01);
        cU10 = MFMA(A1[kf], BUh[0][kf], cU10);
        cU10 = MFMA(A1[kf], BUl[0][kf], cU10);
        cU11 = MFMA(A1[kf], BUh[1][kf], cU11);
        cU11 = MFMA(A1[kf], BUl[1][kf], cU11);
        cW0 = MFMA(AX[kf], BWh[0][kf], cW0);
        cW0 = MFMA(AX[kf], BWl[0][kf], cW0);
        cW1 = MFMA(AX[kf], BWh[1][kf], cW1);
        cW1 = MFMA(AX[kf], BWl[1][kf], cW1);
        cG0 = MFMA(AX[kf], A0[kf], cG0);
        cG1 = MFMA(AX[kf], A1[kf], cG1);
      }
    }
#pragma unroll
    for (int q = 0; q < 4; ++q) {
      const int r = (lo4 << 2) + q;
      L.credU[wv][0][0][r][l15] = cU00[q];
      L.credU[wv][0][1][r][l15] = cU01[q];
      L.credU[wv][1][0][r][l15] = cU10[q];
      L.credU[wv][1][1][r][l15] = cU11[q];
    }
    if (lo4 == 0) {
      L.wxAcc[wv][0][l15] = cW0[0] + cW0[1];
      L.wxAcc[wv][1][l15] = cW1[0] + cW1[1];
      L.gAcc[wv][0][l15] = cG0[0] + cG0[1];
      L.gAcc[wv][1][l15] = cG1[0] + cG1[1];
    }
    bar_lds();  // S1: credU/wx/g visible

    // pre-issue partner-flag read (resolves during update; hits when partners ahead)
    unsigned pv = 0;
    if (t + 1 < S) pv = (ln31 == wg) ? (unsigned)(t + 1) : ALOAD32(ctrp + ln31);

    // ---- update + publish ----
    if (tid < 160) {
      const int i = tid >> 3, c4 = (tid & 7) << 2;
      const int mt = i >> 4, r = i & 15, nt = c4 >> 4, ccc = c4 & 15;
      const f4_t sU = *(const f4_t*)&L.credU[0][mt][nt][r][ccc] +
                      *(const f4_t*)&L.credU[1][mt][nt][r][ccc] +
                      *(const f4_t*)&L.credU[2][mt][nt][r][ccc] +
                      *(const f4_t*)&L.credU[3][mt][nt][r][ccc];
      const f4_t wx = *(const f4_t*)&L.wxAcc[0][nt][ccc] +
                      *(const f4_t*)&L.wxAcc[1][nt][ccc] +
                      *(const f4_t*)&L.wxAcc[2][nt][ccc] +
                      *(const f4_t*)&L.wxAcc[3][nt][ccc];
      const f4_t kv = *(const f4_t*)&L.KVs[i][c4];
      const f4_t oh = *(const f4_t*)&L.ownH[i][c4];
      const float s = sreg;
      const float gpre = s * (L.gAcc[0][mt][r] + L.gAcc[1][mt][r] +
                              L.gAcc[2][mt][r] + L.gAcc[3][mt][r]) + kxreg;
      const float g = sigm_fast(gpre);
      f4_t hn;
      float sq = 0.f;
#pragma unroll
      for (int u = 0; u < 4; ++u) {
        const float cand = tanh_fast(s * sU[u] + kv[u] + wx[u]);
        const float hx = s * oh[u] + g * cand;
        hn[u] = hx;
        sq += hx * hx;
      }
      *(f4_t*)&L.ownH[i][c4] = hn;
      const unsigned d0 = (unsigned)f2bf(hn[0]) | ((unsigned)f2bf(hn[1]) << 16);
      const unsigned d1 = (unsigned)f2bf(hn[2]) | ((unsigned)f2bf(hn[3]) << 16);
      u64_t* hb8 = (u64_t*)Hbuf + (size_t)(nxt2 * B + b) * (NB * 256) +
                   (i << 8) + (wg << 3) + (c4 >> 2);
      ASTORE64(hb8, (u64_t)d0 | ((u64_t)d1 << 32));
      sq += __shfl_xor(sq, 1);
      sq += __shfl_xor(sq, 2);
      sq += __shfl_xor(sq, 4);
      if ((tid & 7) == 0) {
        unsigned* np = (unsigned*)NormP + ((size_t)(nxt2 * B + b) * NB + i) * NWG + wg;
        ASTORE32(np, __float_as_uint(sq));
      }
    }
    bar_full();  // S3: publish drained across all waves

    if (tid == 0) ASTORE32(ctrp + wg, (unsigned)(t + 1));

    if (t + 1 < S) {
      poll32(ctrp, ln31, wg, (unsigned)(t + 1), pv);
      // ---- gather h^{t+1} + NormP + KX, one burst; VALU work overlaps flight ----
      u64_t hv[20];
      const u64_t* g0 = (const u64_t*)Hbuf + (size_t)(nxt2 * B + b) * (NB * 256);
#pragma unroll
      for (int j = 0; j < 20; ++j) hv[j] = ALOAD64(g0 + j * 256 + tid);
      float np0 = 0.f;
      if (tid < 160) {
        const int i = tid >> 3;
        const u64_t* n0 = (const u64_t*)NormP + ((size_t)(nxt2 * B + b) * NB + i) * 16 + ((tid & 7) << 1);
        const u64_t a0 = ALOAD64(n0);
        const u64_t a1 = ALOAD64(n0 + 1);
        np0 = u64lo(a0) + u64hi(a0) + u64lo(a1) + u64hi(a1);
        kxreg = KX[((size_t)b * S + t + 1) * NB + i];
      }
      // xt^{t+1} from prefetched regs; overlaps gather flight
      build_xt(&L.xtA[0][0], tid, evv + mvv);
      if (t + 2 < S) {
        evv = ((const f4_t*)e)[(size_t)(b * S + t + 2) * 256 + tid];
        mvv = ((const f4_t*)m)[(size_t)(b * S + t + 2) * 256 + tid];
      }
      stage_h(L.hnA, tid, hv);
      if (tid < 160) {
        float s0 = np0;
        s0 += __shfl_xor(s0, 1);
        s0 += __shfl_xor(s0, 2);
        s0 += __shfl_xor(s0, 4);
        sreg = rcp_f(sqrtf(s0) + EPS);
      }
    }
    // own-wave staging visible to own-wave ds_reads next phase (stage/build_xt
    // are wave-local; cross-wave hazards gated by the poll — no barrier needed)
    asm volatile("s_waitcnt lgkmcnt(0)" ::: "memory");
  }

  // ---- final: wait all flags at S, reduce NormP(parity 0), write out ----
  poll32(ctrp, ln31, wg, (unsigned)S, 0u);
  if (tid < 160) {
    const int i = tid >> 3, c4 = (tid & 7) << 2;
    const u64_t* np8 = (const u64_t*)NormP + ((size_t)(0 * B + b) * NB + i) * 16 + ((tid & 7) << 1);
    const u64_t x0 = ALOAD64(np8);
    const u64_t x1 = ALOAD64(np8 + 1);
    float sq = u64lo(x0) + u64hi(x0) + u64lo(x1) + u64hi(x1);
    sq += __shfl_xor(sq, 1);
    sq += __shfl_xor(sq, 2);
    sq += __shfl_xor(sq, 4);
    const float sc = rcp_f(sqrtf(sq) + EPS);
    const f4_t oh = *(const f4_t*)&L.ownH[i][c4];
    f4_t ov;
#pragma unroll
    for (int u = 0; u < 4; ++u) ov[u] = sc * oh[u];
    *(f4_t*)(out + (size_t)b * NB * D + (size_t)i * D + (wg << 5) + c4) = ov;
  }
}

}  // namespace

extern "C" void kernel_launch(void* const* d_in, const int* in_sizes, int n_in,
                              void* d_out, int out_size, void* d_ws, size_t ws_size,
                              hipStream_t stream) {
  const float* e = (const float*)d_in[0];
  const float* m = (const float*)d_in[1];
  const float* state = (const float*)d_in[2];
  const float* U = (const float*)d_in[3];
  const float* V = (const float*)d_in[4];
  const float* W = (const float*)d_in[5];
  const float* keys = (const float*)d_in[6];
  float* out = (float*)d_out;
  char* ws = (char*)d_ws;

  unsigned* Hbuf = (unsigned*)(ws + OFF_HBUF);
  float* NormP = (float*)(ws + OFF_NORM);
  int* ctr = (int*)(ws + OFF_CTR);
  float* KV = (float*)(ws + OFF_KV);
  float* KX = (float*)(ws + OFF_KX);
  unsigned short* Uhi = (unsigned short*)(ws + OFF_UHI);
  unsigned short* Ulo = (unsigned short*)(ws + OFF_ULO);
  unsigned short* Whi = (unsigned short*)(ws + OFF_WHI);
  unsigned short* Wlo = (unsigned short*)(ws + OFF_WLO);

  k_convert<<<512, 256, 0, stream>>>(U, W, Uhi, Ulo, Whi, Wlo);
  k_kv<<<16, 256, 0, stream>>>(keys, V, KV);
  k_kx<<<B * S, 256, 0, stream>>>(e, m, keys, KX);
  k_state<<<342, 256, 0, stream>>>(state, Hbuf, NormP, ctr);
  k_rnn<<<B * NWG, 256, 0, stream>>>(e, m, state, KX, KV, Uhi, Ulo, Whi, Wlo,
                                     Hbuf, NormP, ctr, out);
}

// Round 8
// 11369.782 us; speedup vs baseline: 1.9872x; 1.0261x over previous
//
#include <hip/hip_runtime.h>
#include <cstdint>
#include <cstddef>

namespace {

constexpr int D   = 1024;
constexpr int NB  = 20;
constexpr int B   = 8;
constexpr int S   = 2048;
constexpr int NWG = 32;      // workgroups cooperating per batch
constexpr float EPS = 1e-8f;

typedef __attribute__((ext_vector_type(4))) float f4_t;
typedef __attribute__((ext_vector_type(8))) short s8_t;
typedef unsigned long long u64_t;

__device__ __forceinline__ unsigned short f2bf(float f) {
  unsigned u = __float_as_uint(f);
  u += 0x7fffu + ((u >> 16) & 1u);     // RNE
  return (unsigned short)(u >> 16);
}
__device__ __forceinline__ float bf2f(unsigned short h) {
  return __uint_as_float(((unsigned)h) << 16);
}
__device__ __forceinline__ float u64lo(u64_t x) { return __uint_as_float((unsigned)x); }
__device__ __forceinline__ float u64hi(u64_t x) { return __uint_as_float((unsigned)(x >> 32)); }
__device__ __forceinline__ float rcp_f(float x) { return __builtin_amdgcn_rcpf(x); }
__device__ __forceinline__ float sigm_fast(float x) { return rcp_f(1.0f + __expf(-x)); }
__device__ __forceinline__ float tanh_fast(float x) {
  const float e = __expf(2.0f * x);
  return 1.0f - 2.0f * rcp_f(e + 1.0f);
}

#define MFMA(a, b, c) __builtin_amdgcn_mfma_f32_16x16x32_bf16((a), (b), (c), 0, 0, 0)
#define ALOAD64(p) __hip_atomic_load((p), __ATOMIC_RELAXED, __HIP_MEMORY_SCOPE_AGENT)
#define ASTORE64(p, v) __hip_atomic_store((p), (v), __ATOMIC_RELAXED, __HIP_MEMORY_SCOPE_AGENT)
#define ALOAD32(p) __hip_atomic_load((p), __ATOMIC_RELAXED, __HIP_MEMORY_SCOPE_AGENT)
#define ASTORE32(p, v) __hip_atomic_store((p), (v), __ATOMIC_RELAXED, __HIP_MEMORY_SCOPE_AGENT)

// ---- workspace layout (bytes) ----
constexpr size_t OFF_HBUF = 0;                                   // u32 [2][B][NB][512]  (bf16 pairs)
constexpr size_t OFF_NORM = OFF_HBUF + 2ull * B * NB * 512 * 4;  // f32 [2][B][NB][NWG]
constexpr size_t OFF_CTR  = OFF_NORM + 2ull * B * NB * NWG * 4;  // u32 [B][32] per-block step flags
constexpr size_t OFF_KV   = OFF_CTR + (size_t)B * 32 * 4;        // f32 [NB][D]
constexpr size_t OFF_KX   = OFF_KV + (size_t)NB * D * 4;         // f32 [B*S][NB]
constexpr size_t OFF_UHI  = OFF_KX + (size_t)B * S * NB * 4;     // u16 [D][D]
constexpr size_t OFF_ULO  = OFF_UHI + (size_t)D * D * 2;
constexpr size_t OFF_WHI  = OFF_ULO + (size_t)D * D * 2;
constexpr size_t OFF_WLO  = OFF_WHI + (size_t)D * D * 2;

// ---------------- init kernels ----------------

__global__ void k_convert(const float* __restrict__ U, const float* __restrict__ W,
                          unsigned short* __restrict__ Uhi, unsigned short* __restrict__ Ulo,
                          unsigned short* __restrict__ Whi, unsigned short* __restrict__ Wlo) {
  const int n = D * D;
  for (int i = blockIdx.x * blockDim.x + threadIdx.x; i < n; i += gridDim.x * blockDim.x) {
    float u = U[i];
    unsigned short h = f2bf(u);
    Uhi[i] = h;
    Ulo[i] = f2bf(u - bf2f(h));
    float w = W[i];
    h = f2bf(w);
    Whi[i] = h;
    Wlo[i] = f2bf(w - bf2f(h));
  }
}

// KV[i][j] = keys[i] . V[j]
__global__ void k_kv(const float* __restrict__ keys, const float* __restrict__ V,
                     float* __restrict__ KV) {
  const int tid = threadIdx.x;
  const int j = blockIdx.x * 64 + (tid >> 2);
  const int kq = tid & 3;
  const f4_t* v4 = (const f4_t*)(V + (size_t)j * D + kq * 256);
  const f4_t* k4base = (const f4_t*)keys;
  float acc[NB];
#pragma unroll
  for (int i = 0; i < NB; ++i) acc[i] = 0.f;
  for (int q = 0; q < 64; ++q) {
    const f4_t v = v4[q];
#pragma unroll
    for (int i = 0; i < NB; ++i) {
      const f4_t kk = k4base[i * 256 + kq * 64 + q];
      acc[i] += kk[0] * v[0] + kk[1] * v[1] + kk[2] * v[2] + kk[3] * v[3];
    }
  }
#pragma unroll
  for (int i = 0; i < NB; ++i) {
    float s = acc[i];
    s += __shfl_xor(s, 1);
    s += __shfl_xor(s, 2);
    if (kq == 0) KV[(size_t)i * D + j] = s;
  }
}

// KX[bt][i] = keys[i] . (e[bt]+m[bt])
__global__ void k_kx(const float* __restrict__ e, const float* __restrict__ m,
                     const float* __restrict__ keys, float* __restrict__ KX) {
  __shared__ f4_t xs[256];
  __shared__ float part[NB][8];
  const int bt = blockIdx.x, tid = threadIdx.x;
  xs[tid] = ((const f4_t*)e)[(size_t)bt * 256 + tid] + ((const f4_t*)m)[(size_t)bt * 256 + tid];
  __syncthreads();
  if (tid < 160) {
    const int i = tid >> 3, s8 = tid & 7;
    float acc = 0.f;
    const f4_t* k4 = (const f4_t*)keys + i * 256 + s8 * 32;
    for (int q = 0; q < 32; ++q) {
      const f4_t kk = k4[q];
      const f4_t xx = xs[s8 * 32 + q];
      acc += kk[0] * xx[0] + kk[1] * xx[1] + kk[2] * xx[2] + kk[3] * xx[3];
    }
    part[i][s8] = acc;
  }
  __syncthreads();
  if (tid < NB) {
    float s = 0.f;
#pragma unroll
    for (int q = 0; q < 8; ++q) s += part[tid][q];
    KX[(size_t)bt * NB + tid] = s;
  }
}

__global__ void k_state(const float* __restrict__ state, unsigned* __restrict__ Hbuf,
                        float* __restrict__ NormP, int* __restrict__ ctr) {
  const int idx = blockIdx.x * 256 + threadIdx.x;
  if (idx < B * NB * 512) {
    const int r = idx % (NB * 512);
    const int i = r >> 9, d2 = (r & 511) << 1;
    const unsigned short a = f2bf(state[i * D + d2]);
    const unsigned short c = f2bf(state[i * D + d2 + 1]);
    Hbuf[idx] = (unsigned)a | ((unsigned)c << 16);
  }
  const int j = idx - B * NB * 512;
  if (j >= 0 && j < B * NB * NWG) NormP[j] = 1.0f / 32.0f;  // sumsq=1 -> s=1 exactly
  const int q = idx - B * NB * 512 - B * NB * NWG;
  if (q >= 0 && q < B * 32) ctr[q] = 0;
}

// ---------------- persistent recurrence kernel ----------------
// r6 base (11.67ms) + two scheduling changes:
//   * cW (W·x) MFMAs moved into the GATHER SHADOW: in the exchange region,
//     after issuing the 20 h-gather loads, build xt^{t+1}, reload AX frags and
//     run the 32 cW MFMAs while the gather is in flight. AX + cW accumulators
//     persist in registers into the next phase (cG reuses AX; wxAcc is written
//     from the persisted cW). This converts ~400cy of gather-latency stall
//     into useful work and shortens the serial MFMA section.
//   * 4-wave update: ln<40, i=wv*5+(ln>>3), c4=(ln&7)<<2. 40 units/wave
//     (rows 0-4/5-9/10-14/15-19), sq-reduce stays within 8-lane groups;
//     publish stores and their drains spread across all 4 waves (was: waves
//     0/1 doing 64 units each, wave 3 idle).
// Protocol per phase t (unchanged from r6):
//   MFMA(cU,cG) -> S1 (lds barrier) -> update+publish -> S3 (full drain)
//   flag := t+1 -> poll 32 same-batch flags >= t+1
//   gather-issue -> build_xt -> cW MFMAs -> stage -> per-wave lgkmcnt(0)
// Parity-reuse safety: flag >= t+1 implies that block finished gathering
// h^t (parity t&1); a writer of h^{t+2} (same parity) polls >= t+1 before
// its update, so no overwrite race.

struct __align__(16) LdsT {
  unsigned short hnA[NB * 1024];    // raw bf16 h, swizzled               (40 KB)
  unsigned short xtA[2][1024];      // xt hi/lo rows                       (4 KB)
  float credU[4][2][2][16][20];     // [wv][mt][nt][row][col pad20]       (20 KB)
  float wxAcc[4][2][16];            // [wv][nt][col]
  float gAcc[4][2][16];             // [wv][mt][col]
  float KVs[NB][32];
  float ownH[NB][32];               // fp32 unnormalized h slice
  float pad_force_1_block_per_cu[3072];  // lift LDS >80KB so 2 blocks never share a CU
};

__device__ __forceinline__ void build_xt(unsigned short* xt /* [2][1024] */, int tid, f4_t x) {
  const unsigned short h0 = f2bf(x[0]), h1 = f2bf(x[1]), h2 = f2bf(x[2]), h3 = f2bf(x[3]);
  const unsigned short u0 = f2bf(x[0] - bf2f(h0)), u1 = f2bf(x[1] - bf2f(h1));
  const unsigned short u2 = f2bf(x[2] - bf2f(h2)), u3 = f2bf(x[3] - bf2f(h3));
  const int kp = tid << 2;
  *(unsigned*)&xt[kp] = (unsigned)h0 | ((unsigned)h1 << 16);
  *(unsigned*)&xt[kp + 2] = (unsigned)h2 | ((unsigned)h3 << 16);
  *(unsigned*)&xt[1024 + kp] = (unsigned)u0 | ((unsigned)u1 << 16);
  *(unsigned*)&xt[1024 + kp + 2] = (unsigned)u2 | ((unsigned)u3 << 16);
}

__device__ __forceinline__ void stage_h(unsigned short* hn, int tid, const u64_t* hv) {
  const int blkk = tid >> 1;
  const int half = (tid & 1) << 2;
#pragma unroll
  for (int j = 0; j < 20; ++j)
    *(u64_t*)&hn[(j << 10) + ((blkk ^ (j & 15)) << 3) + half] = hv[j];
}

// lds-only barrier: LDS writes visible, VMEM ops stay in flight across it.
__device__ __forceinline__ void bar_lds() {
  asm volatile("s_waitcnt lgkmcnt(0)\n\ts_barrier" ::: "memory");
}
// full barrier: all LDS + VMEM (incl. agent-scope publish stores) drained.
__device__ __forceinline__ void bar_full() {
  asm volatile("s_waitcnt vmcnt(0) lgkmcnt(0)\n\ts_barrier" ::: "memory");
}

// poll until all 32 per-block flags reach tgt; own slot (wg) substituted since
// our block's publishes are drained (S3) before any wave reaches this call.
// pv = pre-issued first read.
__device__ __forceinline__ void poll32(const unsigned* fb, int ln31, int wg,
                                       unsigned tgt, unsigned pv) {
  if (__ballot(pv >= tgt) == ~0ull) return;
  for (;;) {
    const unsigned v = (ln31 == wg) ? tgt : ALOAD32(fb + ln31);
    if (__ballot(v >= tgt) == ~0ull) return;
    __builtin_amdgcn_s_sleep(1);
  }
}

__launch_bounds__(256, 1)
__global__ void k_rnn(const float* __restrict__ e, const float* __restrict__ m,
                      const float* __restrict__ state,
                      const float* __restrict__ KX, const float* __restrict__ KV,
                      const unsigned short* __restrict__ Uhi, const unsigned short* __restrict__ Ulo,
                      const unsigned short* __restrict__ Whi, const unsigned short* __restrict__ Wlo,
                      unsigned* __restrict__ Hbuf, float* __restrict__ NormP,
                      int* __restrict__ ctr, float* __restrict__ out) {
  __shared__ LdsT L;
  const int tid = threadIdx.x;
  const int b = blockIdx.x >> 5;                  // batch 0..7 (scattered over XCDs)
  const int wg = blockIdx.x & 31;                 // column slice 0..31
  const int wv = tid >> 6;
  const int ln = tid & 63;
  const int l15 = ln & 15;
  const int lo4 = ln >> 4;
  const int ln31 = tid & 31;
  unsigned* ctrp = (unsigned*)ctr + b * 32;

  // update-section unit mapping: 40 units per wave (all 4 waves active)
  const bool uact = (ln < 40);
  const int ui = wv * 5 + (ln >> 3);              // row 0..19
  const int uc4 = (ln & 7) << 2;                  // col-group 0,4,..,28

  // resident B-fragments: U and W column slices, bf16 hi/lo, this wave's k-chunk.
  s8_t BUh[2][8], BUl[2][8], BWh[2][8], BWl[2][8];
  {
    const int rowb = (wg << 5) + l15;
#pragma unroll
    for (int nt = 0; nt < 2; ++nt)
#pragma unroll
      for (int kf = 0; kf < 8; ++kf) {
        const size_t off = (size_t)(rowb + nt * 16) * D + (wv << 8) + (kf << 5) + (lo4 << 3);
        BUh[nt][kf] = *(const s8_t*)(Uhi + off);
        BUl[nt][kf] = *(const s8_t*)(Ulo + off);
        BWh[nt][kf] = *(const s8_t*)(Whi + off);
        BWl[nt][kf] = *(const s8_t*)(Wlo + off);
      }
  }
  if (tid < 160) {
    const int i = tid >> 3, c4 = (tid & 7) << 2;
    *(f4_t*)&L.ownH[i][c4] = *(const f4_t*)(state + (size_t)i * D + (wg << 5) + c4);
    *(f4_t*)&L.KVs[i][c4] = *(const f4_t*)(KV + (size_t)i * D + (wg << 5) + c4);
  }

  f4_t evv, mvv;
  float sreg = 1.f;   // exact: initial state pre-normalized (NormP=1/32)
  float kxreg = 0.f;

  // persisted across phases: x fragments + W·x accumulators for current step
  s8_t AX[8];
  f4_t cWa0 = {0, 0, 0, 0}, cWa1 = {0, 0, 0, 0};

  // ---- bootstrap: stage step 0, preload AX(0), compute cW(0) ----
  {
    u64_t hv[20];
    const u64_t* hb8 = (const u64_t*)Hbuf + (size_t)(0 * B + b) * (NB * 256);
#pragma unroll
    for (int j = 0; j < 20; ++j) hv[j] = ALOAD64(hb8 + j * 256 + tid);
    const f4_t x0 = ((const f4_t*)e)[(size_t)(b * S) * 256 + tid] +
                    ((const f4_t*)m)[(size_t)(b * S) * 256 + tid];
    build_xt(&L.xtA[0][0], tid, x0);
    stage_h(L.hnA, tid, hv);
    if (uact) kxreg = KX[(size_t)(b * S) * NB + ui];
    evv = ((const f4_t*)e)[(size_t)(b * S + 1) * 256 + tid];
    mvv = ((const f4_t*)m)[(size_t)(b * S + 1) * 256 + tid];
    asm volatile("s_waitcnt lgkmcnt(0)" ::: "memory");  // own-wave xtA/hnA visible
    const unsigned short* xb = &L.xtA[0][0];
#pragma unroll
    for (int kf = 0; kf < 8; ++kf) {
      const int blk = (wv << 5) + (kf << 2) + lo4;
      AX[kf] = *(const s8_t*)&xb[(l15 & 1) * 1024 + (blk << 3)];
    }
#pragma unroll
    for (int kf = 0; kf < 8; ++kf) {
      cWa0 = MFMA(AX[kf], BWh[0][kf], cWa0);
      cWa0 = MFMA(AX[kf], BWl[0][kf], cWa0);
      cWa1 = MFMA(AX[kf], BWh[1][kf], cWa1);
      cWa1 = MFMA(AX[kf], BWl[1][kf], cWa1);
    }
  }
  __syncthreads();

  for (int t = 0; t < S; ++t) {
    const int nxt2 = (t + 1) & 1;

    // ---- MFMA: cU (h@U^T hi/lo) + cG (x.h gate); cW already done last phase ----
    f4_t cU00 = {0, 0, 0, 0}, cU01 = {0, 0, 0, 0}, cU10 = {0, 0, 0, 0}, cU11 = {0, 0, 0, 0};
    f4_t cG0 = {0, 0, 0, 0}, cG1 = {0, 0, 0, 0};
    {
      const unsigned short* hb = L.hnA;
      const int r1 = 16 + (l15 < 4 ? l15 : 3);  // rows 20..31 duplicate row 19 (ignored)
      s8_t A0[8], A1[8];
#pragma unroll
      for (int kf = 0; kf < 8; ++kf) {
        const int blk = (wv << 5) + (kf << 2) + lo4;  // 8-elem k-block index, 0..127
        A0[kf] = *(const s8_t*)&hb[(l15 << 10) + ((blk ^ l15) << 3)];
        A1[kf] = *(const s8_t*)&hb[(r1 << 10) + ((blk ^ (r1 & 15)) << 3)];
      }
#pragma unroll
      for (int kf = 0; kf < 8; ++kf) {
        cU00 = MFMA(A0[kf], BUh[0][kf], cU00);
        cU00 = MFMA(A0[kf], BUl[0][kf], cU00);
        cU01 = MFMA(A0[kf], BUh[1][kf], cU01);
        cU01 = MFMA(A0[kf], BUl[1][kf], cU01);
        cU10 = MFMA(A1[kf], BUh[0][kf], cU10);
        cU10 = MFMA(A1[kf], BUl[0][kf], cU10);
        cU11 = MFMA(A1[kf], BUh[1][kf], cU11);
        cU11 = MFMA(A1[kf], BUl[1][kf], cU11);
        cG0 = MFMA(AX[kf], A0[kf], cG0);
        cG1 = MFMA(AX[kf], A1[kf], cG1);
      }
    }
#pragma unroll
    for (int q = 0; q < 4; ++q) {
      const int r = (lo4 << 2) + q;
      L.credU[wv][0][0][r][l15] = cU00[q];
      L.credU[wv][0][1][r][l15] = cU01[q];
      L.credU[wv][1][0][r][l15] = cU10[q];
      L.credU[wv][1][1][r][l15] = cU11[q];
    }
    if (lo4 == 0) {
      L.wxAcc[wv][0][l15] = cWa0[0] + cWa0[1];
      L.wxAcc[wv][1][l15] = cWa1[0] + cWa1[1];
      L.gAcc[wv][0][l15] = cG0[0] + cG0[1];
      L.gAcc[wv][1][l15] = cG1[0] + cG1[1];
    }
    bar_lds();  // S1: credU/wx/g visible

    // pre-issue partner-flag read (resolves during update; hits when partners ahead)
    unsigned pv = 0;
    if (t + 1 < S) pv = (ln31 == wg) ? (unsigned)(t + 1) : ALOAD32(ctrp + ln31);

    // ---- update + publish (4-wave balanced: 40 units per wave) ----
    if (uact) {
      const int i = ui, c4 = uc4;
      const int mt = i >> 4, r = i & 15, nt = c4 >> 4, ccc = c4 & 15;
      const f4_t sU = *(const f4_t*)&L.credU[0][mt][nt][r][ccc] +
                      *(const f4_t*)&L.credU[1][mt][nt][r][ccc] +
                      *(const f4_t*)&L.credU[2][mt][nt][r][ccc] +
                      *(const f4_t*)&L.credU[3][mt][nt][r][ccc];
      const f4_t wx = *(const f4_t*)&L.wxAcc[0][nt][ccc] +
                      *(const f4_t*)&L.wxAcc[1][nt][ccc] +
                      *(const f4_t*)&L.wxAcc[2][nt][ccc] +
                      *(const f4_t*)&L.wxAcc[3][nt][ccc];
      const f4_t kv = *(const f4_t*)&L.KVs[i][c4];
      const f4_t oh = *(const f4_t*)&L.ownH[i][c4];
      const float s = sreg;
      const float gpre = s * (L.gAcc[0][mt][r] + L.gAcc[1][mt][r] +
                              L.gAcc[2][mt][r] + L.gAcc[3][mt][r]) + kxreg;
      const float g = sigm_fast(gpre);
      f4_t hn;
      float sq = 0.f;
#pragma unroll
      for (int u = 0; u < 4; ++u) {
        const float cand = tanh_fast(s * sU[u] + kv[u] + wx[u]);
        const float hx = s * oh[u] + g * cand;
        hn[u] = hx;
        sq += hx * hx;
      }
      *(f4_t*)&L.ownH[i][c4] = hn;
      const unsigned d0 = (unsigned)f2bf(hn[0]) | ((unsigned)f2bf(hn[1]) << 16);
      const unsigned d1 = (unsigned)f2bf(hn[2]) | ((unsigned)f2bf(hn[3]) << 16);
      u64_t* hb8 = (u64_t*)Hbuf + (size_t)(nxt2 * B + b) * (NB * 256) +
                   (i << 8) + (wg << 3) + (c4 >> 2);
      ASTORE64(hb8, (u64_t)d0 | ((u64_t)d1 << 32));
      sq += __shfl_xor(sq, 1);
      sq += __shfl_xor(sq, 2);
      sq += __shfl_xor(sq, 4);
      if ((ln & 7) == 0) {
        unsigned* np = (unsigned*)NormP + ((size_t)(nxt2 * B + b) * NB + i) * NWG + wg;
        ASTORE32(np, __float_as_uint(sq));
      }
    }
    bar_full();  // S3: publish drained across all waves

    if (tid == 0) ASTORE32(ctrp + wg, (unsigned)(t + 1));

    if (t + 1 < S) {
      poll32(ctrp, ln31, wg, (unsigned)(t + 1), pv);
      // ---- issue gather; fill its shadow with xt-build + cW MFMAs ----
      u64_t hv[20];
      const u64_t* g0 = (const u64_t*)Hbuf + (size_t)(nxt2 * B + b) * (NB * 256);
#pragma unroll
      for (int j = 0; j < 20; ++j) hv[j] = ALOAD64(g0 + j * 256 + tid);
      float np0 = 0.f;
      if (uact) {
        const u64_t* n0 = (const u64_t*)NormP + ((size_t)(nxt2 * B + b) * NB + ui) * 16 + ((ln & 7) << 1);
        const u64_t a0 = ALOAD64(n0);
        const u64_t a1 = ALOAD64(n0 + 1);
        np0 = u64lo(a0) + u64hi(a0) + u64lo(a1) + u64hi(a1);
        kxreg = KX[((size_t)b * S + t + 1) * NB + ui];
      }
      asm volatile("" ::: "memory");  // pin load issue order above the cW work
      // xt^{t+1} + cW^{t+1}: independent of the in-flight h gather
      build_xt(&L.xtA[0][0], tid, evv + mvv);
      asm volatile("s_waitcnt lgkmcnt(0)" ::: "memory");  // own-wave xtA visible
      {
        const unsigned short* xb = &L.xtA[0][0];
#pragma unroll
        for (int kf = 0; kf < 8; ++kf) {
          const int blk = (wv << 5) + (kf << 2) + lo4;
          AX[kf] = *(const s8_t*)&xb[(l15 & 1) * 1024 + (blk << 3)];
        }
        cWa0 = (f4_t){0, 0, 0, 0};
        cWa1 = (f4_t){0, 0, 0, 0};
#pragma unroll
        for (int kf = 0; kf < 8; ++kf) {
          cWa0 = MFMA(AX[kf], BWh[0][kf], cWa0);
          cWa0 = MFMA(AX[kf], BWl[0][kf], cWa0);
          cWa1 = MFMA(AX[kf], BWh[1][kf], cWa1);
          cWa1 = MFMA(AX[kf], BWl[1][kf], cWa1);
        }
      }
      stage_h(L.hnA, tid, hv);   // waits the gather; wave-local staging
      if (t + 2 < S) {
        evv = ((const f4_t*)e)[(size_t)(b * S + t + 2) * 256 + tid];
        mvv = ((const f4_t*)m)[(size_t)(b * S + t + 2) * 256 + tid];
      }
      if (uact) {
        float s0 = np0;
        s0 += __shfl_xor(s0, 1);
        s0 += __shfl_xor(s0, 2);
        s0 += __shfl_xor(s0, 4);
        sreg = rcp_f(sqrtf(s0) + EPS);
      }
    }
    // own-wave staging visible to own-wave ds_reads next phase
    asm volatile("s_waitcnt lgkmcnt(0)" ::: "memory");
  }

  // ---- final: wait all flags at S, reduce NormP(parity 0), write out ----
  poll32(ctrp, ln31, wg, (unsigned)S, 0u);
  if (uact) {
    const int i = ui, c4 = uc4;
    const u64_t* np8 = (const u64_t*)NormP + ((size_t)(0 * B + b) * NB + i) * 16 + ((ln & 7) << 1);
    const u64_t x0 = ALOAD64(np8);
    const u64_t x1 = ALOAD64(np8 + 1);
    float sq = u64lo(x0) + u64hi(x0) + u64lo(x1) + u64hi(x1);
    sq += __shfl_xor(sq, 1);
    sq += __shfl_xor(sq, 2);
    sq += __shfl_xor(sq, 4);
    const float sc = rcp_f(sqrtf(sq) + EPS);
    const f4_t oh = *(const f4_t*)&L.ownH[i][c4];
    f4_t ov;
#pragma unroll
    for (int u = 0; u < 4; ++u) ov[u] = sc * oh[u];
    *(f4_t*)(out + (size_t)b * NB * D + (size_t)i * D + (wg << 5) + c4) = ov;
  }
}

}  // namespace

extern "C" void kernel_launch(void* const* d_in, const int* in_sizes, int n_in,
                              void* d_out, int out_size, void* d_ws, size_t ws_size,
                              hipStream_t stream) {
  const float* e = (const float*)d_in[0];
  const float* m = (const float*)d_in[1];
  const float* state = (const float*)d_in[2];
  const float* U = (const float*)d_in[3];
  const float* V = (const float*)d_in[4];
  const float* W = (const float*)d_in[5];
  const float* keys = (const float*)d_in[6];
  float* out = (float*)d_out;
  char* ws = (char*)d_ws;

  unsigned* Hbuf = (unsigned*)(ws + OFF_HBUF);
  float* NormP = (float*)(ws + OFF_NORM);
  int* ctr = (int*)(ws + OFF_CTR);
  float* KV = (float*)(ws + OFF_KV);
  float* KX = (float*)(ws + OFF_KX);
  unsigned short* Uhi = (unsigned short*)(ws + OFF_UHI);
  unsigned short* Ulo = (unsigned short*)(ws + OFF_ULO);
  unsigned short* Whi = (unsigned short*)(ws + OFF_WHI);
  unsigned short* Wlo = (unsigned short*)(ws + OFF_WLO);

  k_convert<<<512, 256, 0, stream>>>(U, W, Uhi, Ulo, Whi, Wlo);
  k_kv<<<16, 256, 0, stream>>>(keys, V, KV);
  k_kx<<<B * S, 256, 0, stream>>>(e, m, keys, KX);
  k_state<<<342, 256, 0, stream>>>(state, Hbuf, NormP, ctr);
  k_rnn<<<B * NWG, 256, 0, stream>>>(e, m, state, KX, KV, Uhi, Ulo, Whi, Wlo,
                                     Hbuf, NormP, ctr, out);
}